// Round 8
// baseline (312.638 us; speedup 1.0000x reference)
//
#include <hip/hip_runtime.h>
#include <math.h>

#define SS   2048
#define HH   2048
#define NH_  32
#define NKV_ 8
#define HD_  64
#define QKVO 3072     // (32 + 2*8) * 64
#define MTOK 4096     // B * S

typedef _Float16 f16x8 __attribute__((ext_vector_type(8)));   // 8 fp16 in 4 VGPRs
typedef _Float16 f16x4 __attribute__((ext_vector_type(4)));   // 4 fp16 in 2 VGPRs
typedef __fp16   fp16x2 __attribute__((ext_vector_type(2))); // cvt_pkrtz return type
typedef float f32x4 __attribute__((ext_vector_type(4)));
typedef int   i32x4 __attribute__((ext_vector_type(4)));      // 16 i8 (A/B frag) or 4 i32 (C/D)

__device__ inline ushort f2h(float f) {
    _Float16 h = (_Float16)f;
    return *(ushort*)&h;
}
__device__ inline f16x4 pk4(float a, float b, float c, float d) {
    union { fp16x2 v2[2]; f16x4 v4; } u;
    u.v2[0] = __builtin_amdgcn_cvt_pkrtz(a, b);
    u.v2[1] = __builtin_amdgcn_cvt_pkrtz(c, d);
    return u.v4;
}
__device__ inline int packi8(float a, float b, float c, float d) {   // values are exact ints
    return ((int)a & 255) | (((int)b & 255) << 8) | (((int)c & 255) << 16) | (((int)d & 255) << 24);
}

__device__ inline void gl_lds16(const void* g, void* l) {
    __builtin_amdgcn_global_load_lds((const __attribute__((address_space(1))) void*)g,
                                     (__attribute__((address_space(3))) void*)l, 16, 0, 0);
}

// ---------------- fused prologue: |w| sums (float4) + rope table ----------------
__global__ __launch_bounds__(256) void prep_kernel(const float* __restrict__ wq,
                                                   const float* __restrict__ wo,
                                                   float* __restrict__ scal,
                                                   float* __restrict__ tab) {
    __shared__ float red[256];
    int bx = blockIdx.x, tid = threadIdx.x;
    if (bx < 2560) {
        const float* src; float* dst; int n4, b0, nb;
        if (bx < 1536) { src = wq; dst = scal + 0; n4 = QKVO * HH / 4; b0 = bx;        nb = 1536; }
        else           { src = wo; dst = scal + 1; n4 = HH * HH / 4;   b0 = bx - 1536; nb = 1024; }
        float acc = 0.f;
        for (int i = b0 * 256 + tid; i < n4; i += nb * 256) {
            float4 v = ((const float4*)src)[i];
            acc += (fabsf(v.x) + fabsf(v.y)) + (fabsf(v.z) + fabsf(v.w));
        }
        red[tid] = acc;
        __syncthreads();
        for (int s = 128; s > 0; s >>= 1) { if (tid < s) red[tid] += red[tid + s]; __syncthreads(); }
        if (tid == 0) atomicAdd(dst, red[0]);
    } else {
        int i = (bx - 2560) * 256 + tid;        // SS*32 threads
        int sp = i >> 5, d = i & 31;
        float inv = (float)pow(10000.0, -(double)d / 32.0);
        float ang = (float)sp * inv;
        tab[sp * 64 + d]      = cosf(ang);
        tab[sp * 64 + 32 + d] = sinf(ang);
    }
}

// ---------------- fused ternary weight quant -> i8 (both weights) ----------------
__global__ __launch_bounds__(256) void wquant_kernel(const float* __restrict__ wq,
                                                     const float* __restrict__ wo,
                                                     int* __restrict__ q1,
                                                     int* __restrict__ q2,
                                                     const float* __restrict__ scal) {
    int bx = blockIdx.x, tid = threadIdx.x;
    const float* src; int* dst; int n4, b0, nb; float mean;
    if (bx < 1536) { src = wq; dst = q1; n4 = QKVO * HH / 4; b0 = bx;        nb = 1536;
                     mean = fmaxf(scal[0] * (1.0f / 6291456.0f), 1e-5f); }
    else           { src = wo; dst = q2; n4 = HH * HH / 4;   b0 = bx - 1536; nb = 1024;
                     mean = fmaxf(scal[1] * (1.0f / 4194304.0f), 1e-5f); }
    float wsc = 1.f / mean;
    for (int i = b0 * 256 + tid; i < n4; i += nb * 256) {
        float4 v = ((const float4*)src)[i];
        dst[i] = packi8(fminf(fmaxf(rintf(v.x * wsc), -1.f), 1.f),
                        fminf(fmaxf(rintf(v.y * wsc), -1.f), 1.f),
                        fminf(fmaxf(rintf(v.z * wsc), -1.f), 1.f),
                        fminf(fmaxf(rintf(v.w * wsc), -1.f), 1.f));
    }
}

// ---------------- RMSNorm + activation quant -> i8 (one block per row, H=2048) ----------------
__global__ __launch_bounds__(256) void rmsq_kernel(const float* __restrict__ x,
                                                   const float* __restrict__ wn,
                                                   int* __restrict__ xq,
                                                   float* __restrict__ xsc) {
    __shared__ float red[256];
    int tid = threadIdx.x;
    const float* xr = x + (size_t)blockIdx.x * HH;
    float4 a = ((const float4*)xr)[tid];
    float4 b = ((const float4*)xr)[tid + 256];
    float s2 = a.x*a.x + a.y*a.y + a.z*a.z + a.w*a.w
             + b.x*b.x + b.y*b.y + b.z*b.z + b.w*b.w;
    red[tid] = s2;
    __syncthreads();
    for (int s = 128; s > 0; s >>= 1) { if (tid < s) red[tid] += red[tid + s]; __syncthreads(); }
    float r = rsqrtf(red[0] * (1.f / HH) + 1e-5f);
    __syncthreads();
    float4 wa = ((const float4*)wn)[tid];
    float4 wb = ((const float4*)wn)[tid + 256];
    float4 na, nb;
    na.x = a.x * r * wa.x; na.y = a.y * r * wa.y; na.z = a.z * r * wa.z; na.w = a.w * r * wa.w;
    nb.x = b.x * r * wb.x; nb.y = b.y * r * wb.y; nb.z = b.z * r * wb.z; nb.w = b.w * r * wb.w;
    float am = fabsf(na.x);
    am = fmaxf(am, fabsf(na.y)); am = fmaxf(am, fabsf(na.z)); am = fmaxf(am, fabsf(na.w));
    am = fmaxf(am, fabsf(nb.x)); am = fmaxf(am, fabsf(nb.y));
    am = fmaxf(am, fabsf(nb.z)); am = fmaxf(am, fabsf(nb.w));
    red[tid] = am;
    __syncthreads();
    for (int s = 128; s > 0; s >>= 1) { if (tid < s) red[tid] = fmaxf(red[tid], red[tid + s]); __syncthreads(); }
    float amax = fmaxf(red[0], 1e-5f);
    float xs = 127.f / amax;
    if (tid == 0) xsc[blockIdx.x] = amax * (1.f / 127.f);
    int* qr = xq + (size_t)blockIdx.x * (HH / 4);
    qr[tid] = packi8(fminf(fmaxf(rintf(na.x * xs), -128.f), 127.f),
                     fminf(fmaxf(rintf(na.y * xs), -128.f), 127.f),
                     fminf(fmaxf(rintf(na.z * xs), -128.f), 127.f),
                     fminf(fmaxf(rintf(na.w * xs), -128.f), 127.f));
    qr[tid + 256] = packi8(fminf(fmaxf(rintf(nb.x * xs), -128.f), 127.f),
                           fminf(fmaxf(rintf(nb.y * xs), -128.f), 127.f),
                           fminf(fmaxf(rintf(nb.z * xs), -128.f), 127.f),
                           fminf(fmaxf(rintf(nb.w * xs), -128.f), 127.f));
}

// ---------------- row absmax quant f16 -> i8 (attention output, H=2048) ----------------
__global__ __launch_bounds__(256) void rowq_kernel(const ushort* __restrict__ x,
                                                   int* __restrict__ xq,
                                                   float* __restrict__ xsc) {
    __shared__ float red[256];
    int tid = threadIdx.x;
    const ushort* xr = x + (size_t)blockIdx.x * HH;
    f16x8 v = *(const f16x8*)&xr[tid * 8];
    float f0 = (float)v[0], f1 = (float)v[1], f2 = (float)v[2], f3 = (float)v[3];
    float f4 = (float)v[4], f5 = (float)v[5], f6 = (float)v[6], f7 = (float)v[7];
    float am = fabsf(f0);
    am = fmaxf(am, fabsf(f1)); am = fmaxf(am, fabsf(f2)); am = fmaxf(am, fabsf(f3));
    am = fmaxf(am, fabsf(f4)); am = fmaxf(am, fabsf(f5));
    am = fmaxf(am, fabsf(f6)); am = fmaxf(am, fabsf(f7));
    red[tid] = am;
    __syncthreads();
    for (int s = 128; s > 0; s >>= 1) { if (tid < s) red[tid] = fmaxf(red[tid], red[tid + s]); __syncthreads(); }
    float amax = fmaxf(red[0], 1e-5f);
    float xs = 127.f / amax;
    if (tid == 0) xsc[blockIdx.x] = amax * (1.f / 127.f);
    int* qr = xq + (size_t)blockIdx.x * (HH / 4);
    qr[tid * 2]     = packi8(fminf(fmaxf(rintf(f0 * xs), -128.f), 127.f),
                             fminf(fmaxf(rintf(f1 * xs), -128.f), 127.f),
                             fminf(fmaxf(rintf(f2 * xs), -128.f), 127.f),
                             fminf(fmaxf(rintf(f3 * xs), -128.f), 127.f));
    qr[tid * 2 + 1] = packi8(fminf(fmaxf(rintf(f4 * xs), -128.f), 127.f),
                             fminf(fmaxf(rintf(f5 * xs), -128.f), 127.f),
                             fminf(fmaxf(rintf(f6 * xs), -128.f), 127.f),
                             fminf(fmaxf(rintf(f7 * xs), -128.f), 127.f));
}

// ------- i8 MFMA GEMM, BK=128 swizzled, double-buffered async pipeline (1 barrier/iter) -----
#define GSTAGE(Abuf, Bbuf, kk) do {                                         \
        _Pragma("unroll")                                                   \
        for (int i_ = 0; i_ < 4; ++i_) {                                    \
            gl_lds16(Arow + (size_t)(i_ * 8) * K + (kk), (Abuf) + (w << 12) + i_ * 1024); \
            gl_lds16(Brow + (size_t)(i_ * 8) * K + (kk), (Bbuf) + (w << 12) + i_ * 1024); \
        }                                                                   \
    } while (0)

__global__ __launch_bounds__(256) void gemm_i8_kernel(const char* __restrict__ A,
                                                      const char* __restrict__ B,
                                                      float* __restrict__ C,
                                                      const float* __restrict__ rsc,
                                                      const float* __restrict__ wsum,
                                                      float inv_n, int N, int K) {
    __shared__ __align__(16) char Alds[2][128 * 128];
    __shared__ __align__(16) char Blds[2][128 * 128];
    int tid = threadIdx.x;
    int lane = tid & 63, w = tid >> 6;
    int quad = lane >> 4, l15 = lane & 15;
    int m0 = blockIdx.y << 7, n0 = blockIdx.x << 7;
    int wm = (w >> 1) << 6, wn = (w & 1) << 6;
    int srow = (w << 5) + (lane >> 3);            // + i*8 per staging instr
    int scol = ((lane & 7) ^ (lane >> 3)) << 4;   // XOR swizzle (row&7 == lane>>3)
    const char* Arow = A + (size_t)(m0 + srow) * K + scol;
    const char* Brow = B + (size_t)(n0 + srow) * K + scol;

    i32x4 acc[4][4] = {};
    GSTAGE(Alds[0], Blds[0], 0);
    __syncthreads();
    int buf = 0;
    for (int k0 = 0; k0 < K; k0 += 128) {
        if (k0 + 128 < K) GSTAGE(Alds[buf ^ 1], Blds[buf ^ 1], k0 + 128);
        const char* Ab = Alds[buf];
        const char* Bb = Blds[buf];
        #pragma unroll
        for (int ks = 0; ks < 2; ++ks) {
            i32x4 af[4], bfr[4];
            #pragma unroll
            for (int i = 0; i < 4; ++i) {
                int ra = wm + i * 16 + l15;       // ra&7 == l15&7
                int ca = ((ks * 4 + quad) ^ (l15 & 7)) << 4;
                af[i]  = *(const i32x4*)&Ab[ra * 128 + ca];
                bfr[i] = *(const i32x4*)&Bb[(wn + i * 16 + l15) * 128 + ca];
            }
            #pragma unroll
            for (int i = 0; i < 4; ++i)
                #pragma unroll
                for (int j = 0; j < 4; ++j)
                    acc[i][j] = __builtin_amdgcn_mfma_i32_16x16x64_i8(af[i], bfr[j], acc[i][j], 0, 0, 0);
        }
        __syncthreads();
        buf ^= 1;
    }

    float wsc = fmaxf(wsum[0] * inv_n, 1e-5f);
    #pragma unroll
    for (int i = 0; i < 4; ++i) {
        #pragma unroll
        for (int r = 0; r < 4; ++r) {
            int row = m0 + wm + i * 16 + quad * 4 + r;
            float s = rsc[row] * wsc;
            #pragma unroll
            for (int j = 0; j < 4; ++j) {
                int col = n0 + wn + j * 16 + l15;
                C[(size_t)row * N + col] = (float)acc[i][j][r] * s;
            }
        }
    }
}

// ---------------- QKV i8 GEMM (dbuf pipeline) with fused RoPE + fp16 epilogue ----------------
__global__ __launch_bounds__(256) void gemm_qkv_kernel(const char* __restrict__ A,
                                                       const char* __restrict__ B,
                                                       const float* __restrict__ rsc,
                                                       const float* __restrict__ wsum,
                                                       float inv_n,
                                                       const float* __restrict__ tab,
                                                       ushort* __restrict__ qh,
                                                       ushort* __restrict__ kh,
                                                       ushort* __restrict__ vT) {
    const int K = HH;
    __shared__ __align__(16) char Alds[2][128 * 128];
    __shared__ __align__(16) char Blds[2][128 * 128];
    int tid = threadIdx.x;
    int lane = tid & 63, w = tid >> 6;
    int quad = lane >> 4, l15 = lane & 15;
    int m0 = blockIdx.y << 7, n0 = blockIdx.x << 7;
    int wm = (w >> 1) << 6, wn = (w & 1) << 6;
    int srow = (w << 5) + (lane >> 3);
    int scol = ((lane & 7) ^ (lane >> 3)) << 4;
    const char* Arow = A + (size_t)(m0 + srow) * K + scol;
    const char* Brow = B + (size_t)(n0 + srow) * K + scol;

    i32x4 acc[4][4] = {};
    GSTAGE(Alds[0], Blds[0], 0);
    __syncthreads();
    int buf = 0;
    for (int k0 = 0; k0 < K; k0 += 128) {
        if (k0 + 128 < K) GSTAGE(Alds[buf ^ 1], Blds[buf ^ 1], k0 + 128);
        const char* Ab = Alds[buf];
        const char* Bb = Blds[buf];
        #pragma unroll
        for (int ks = 0; ks < 2; ++ks) {
            i32x4 af[4], bfr[4];
            #pragma unroll
            for (int i = 0; i < 4; ++i) {
                int ca = ((ks * 4 + quad) ^ (l15 & 7)) << 4;
                af[i]  = *(const i32x4*)&Ab[(wm + i * 16 + l15) * 128 + ca];
                bfr[i] = *(const i32x4*)&Bb[(wn + i * 16 + l15) * 128 + ca];
            }
            #pragma unroll
            for (int i = 0; i < 4; ++i)
                #pragma unroll
                for (int j = 0; j < 4; ++j)
                    acc[i][j] = __builtin_amdgcn_mfma_i32_16x16x64_i8(af[i], bfr[j], acc[i][j], 0, 0, 0);
        }
        __syncthreads();
        buf ^= 1;
    }

    float wsc = fmaxf(wsum[0] * inv_n, 1e-5f);
    int region = (n0 + wn) >> 6;                 // head index within qkv cols
    if (region < 32) {                           // Q (rope, x0.125, xlog2(e) folded for exp2 softmax)
        const float qscale = 0.125f * 1.44269504088896f;
        #pragma unroll
        for (int i = 0; i < 4; ++i)
            #pragma unroll
            for (int r = 0; r < 4; ++r) {
                int row = m0 + wm + i * 16 + quad * 4 + r;
                float s = rsc[row] * wsc;
                int sp = row & (SS - 1);
                #pragma unroll
                for (int j = 0; j < 2; ++j) {
                    int d = j * 16 + l15;
                    float c = tab[sp * 64 + d], sn = tab[sp * 64 + 32 + d];
                    float xr = (float)acc[i][j][r] * s, xi = (float)acc[i][j + 2][r] * s;
                    qh[(size_t)row * HH + region * 64 + d]      = f2h((xr * c - xi * sn) * qscale);
                    qh[(size_t)row * HH + region * 64 + d + 32] = f2h((xr * sn + xi * c) * qscale);
                }
            }
    } else if (region < 40) {                    // K (rope)
        int kv = region - 32;
        #pragma unroll
        for (int i = 0; i < 4; ++i)
            #pragma unroll
            for (int r = 0; r < 4; ++r) {
                int row = m0 + wm + i * 16 + quad * 4 + r;
                float s = rsc[row] * wsc;
                int sp = row & (SS - 1);
                #pragma unroll
                for (int j = 0; j < 2; ++j) {
                    int d = j * 16 + l15;
                    float c = tab[sp * 64 + d], sn = tab[sp * 64 + 32 + d];
                    float xr = (float)acc[i][j][r] * s, xi = (float)acc[i][j + 2][r] * s;
                    kh[(size_t)row * (NKV_ * 64) + kv * 64 + d]      = f2h(xr * c - xi * sn);
                    kh[(size_t)row * (NKV_ * 64) + kv * 64 + d + 32] = f2h(xr * sn + xi * c);
                }
            }
    } else {                                     // V -> transposed [b][kv][d][t-permuted], packed 4 rows
        // within each 64-half tile, half position t' = quad(t)*16 + tc(t)*4 + e(t)
        // where t = tc*16 + quad*4 + e  (so attn PV reads 32B contiguous per quad)
        int kv = region - 40;
        #pragma unroll
        for (int i = 0; i < 4; ++i) {
            int row0 = m0 + wm + i * 16 + quad * 4;
            int bb = row0 >> 11, sr = row0 & (SS - 1);
            int tp = (sr & ~63) + (((sr >> 2) & 3) << 4) + (((sr >> 4) & 3) << 2);  // e=0 base
            float sc0 = rsc[row0 + 0] * wsc;
            float sc1 = rsc[row0 + 1] * wsc;
            float sc2 = rsc[row0 + 2] * wsc;
            float sc3 = rsc[row0 + 3] * wsc;
            #pragma unroll
            for (int j = 0; j < 4; ++j) {
                int d = j * 16 + l15;
                ushort4 o;
                o.x = f2h((float)acc[i][j][0] * sc0);
                o.y = f2h((float)acc[i][j][1] * sc1);
                o.z = f2h((float)acc[i][j][2] * sc2);
                o.w = f2h((float)acc[i][j][3] * sc3);
                *(ushort4*)&vT[(((size_t)(bb * NKV_ + kv)) * 64 + d) * SS + tp] = o;
            }
        }
    }
}
#undef GSTAGE

// ---------------- MFMA flash attention: swapped-QK in-register softmax, no Ps LDS ----------
// One q-tile per block (UNPAIRED): grid 32x16x2 = 1024 blocks = 4/CU resident (32KB LDS,
// 64 VGPR -> 5 max) = 4 waves/SIMD for latency hiding; imbalance (nt=1..32) absorbed by
// 4-deep residency + longest-first ordering. Swapped QK (mfma(K,Q)): lane (quad,l15) holds
// P[qrow=l15][t] -> row-sum lane-local; P frags for K=16 PV from 8 cvt_pkrtz/head, zero
// shuffles/LDS. vT t-permuted (t'=quad*16+tc*4+e) -> V frags 32B contiguous, 2x b128/jo.
// 2 GQA heads/block share K/V staging. exp2 softmax (log2e folded into Q scale).
__global__ __launch_bounds__(256, 4) void attn_mfma_kernel(const ushort* __restrict__ qh,
                                                           const ushort* __restrict__ kh,
                                                           const ushort* __restrict__ vT,
                                                           ushort* __restrict__ attno) {
    __shared__ __align__(16) ushort Kl[2][4096];   // [buf][t64 * 64] swizzled
    __shared__ __align__(16) ushort Vl[2][4096];   // [buf][d64 * 64] swizzled (t'-permuted)
    int tid = threadIdx.x;
    int lane = tid & 63, w = tid >> 6;
    int quad = lane >> 4, l15 = lane & 15;
    int tq = 31 - (int)blockIdx.x;                   // longest-first
    int h0 = blockIdx.y << 1;                        // heads h0, h0+1 (same kv head, G=4)
    int b  = blockIdx.z;
    int khd = blockIdx.y >> 1;
    int s0 = tq << 6;
    int nt = tq + 1;

    int rl = lane >> 3;                              // staging row-within-8
    int cl = ((lane & 7) ^ rl) << 3;                 // pre-swizzled source chunk (halfs)
    const ushort* kbase = kh + ((size_t)b * SS + (w << 4) + rl) * (NKV_ * 64) + (khd << 6) + cl;
    const ushort* vbase = vT + ((((size_t)(b * NKV_ + khd)) << 6) + (w << 4) + rl) * SS + cl;

#define STAGE(bb, tt) do {                                              \
        gl_lds16(kbase + (size_t)(tt) * 512,       &Kl[bb][w << 10]);       \
        gl_lds16(kbase + (size_t)((tt) + 8) * 512, &Kl[bb][(w << 10) + 512]); \
        gl_lds16(vbase + (tt),                     &Vl[bb][w << 10]);       \
        gl_lds16(vbase + 8 * SS + (tt),            &Vl[bb][(w << 10) + 512]); \
    } while (0)

    int cs = l15 & 7;                                // row&7 for frag rows *16+l15
    int cur = 0;

    STAGE(0, 0);

    const ushort* qp = qh + ((size_t)(b * SS + s0 + (w << 4) + l15)) * HH + (h0 << 6) + (quad << 3);
    f16x8 qa0 = *(const f16x8*)qp;              // head0 d[0..32)
    f16x8 qa1 = *(const f16x8*)(qp + 32);       // head0 d[32..64)
    f16x8 qb0 = *(const f16x8*)(qp + 64);       // head1
    f16x8 qb1 = *(const f16x8*)(qp + 96);

    __syncthreads();                                 // drains initial stage

    float lpa = 0.f, lpb = 0.f;
    f32x4 ofa[4] = {};
    f32x4 ofb[4] = {};

    for (int it = 0; it < nt; ++it) {
        if (it + 1 < nt) STAGE(cur ^ 1, (it + 1) << 6);   // prefetch overlaps compute below

        const ushort* Kb = Kl[cur];
        const ushort* Vb = Vl[cur];

        // swapped QK: sa[j] holds S[t = 16j + 4quad + r][qrow = l15]
        f32x4 sa[4] = {}, sb[4] = {};
        __builtin_amdgcn_s_setprio(1);
        #pragma unroll
        for (int j = 0; j < 4; ++j) {
            const ushort* kr = &Kb[(j * 16 + l15) << 6];
            f16x8 kf0 = *(const f16x8*)&kr[(quad ^ cs) << 3];
            f16x8 kf1 = *(const f16x8*)&kr[((quad | 4) ^ cs) << 3];
            sa[j] = __builtin_amdgcn_mfma_f32_16x16x32_f16(kf0, qa0, sa[j], 0, 0, 0);
            sa[j] = __builtin_amdgcn_mfma_f32_16x16x32_f16(kf1, qa1, sa[j], 0, 0, 0);
            sb[j] = __builtin_amdgcn_mfma_f32_16x16x32_f16(kf0, qb0, sb[j], 0, 0, 0);
            sb[j] = __builtin_amdgcn_mfma_f32_16x16x32_f16(kf1, qb1, sb[j], 0, 0, 0);
        }
        __builtin_amdgcn_s_setprio(0);

        if (it == nt - 1) {             // causal mask: t = 16j+4quad+r vs qrow' = w*16+l15
            int qr = (w << 4) + l15;
            #pragma unroll
            for (int j = 0; j < 4; ++j)
                #pragma unroll
                for (int r = 0; r < 4; ++r)
                    if (16 * j + quad * 4 + r > qr) { sa[j][r] = -INFINITY; sb[j][r] = -INFINITY; }
        }

        // exp2 softmax + lane-local row sums + in-register P fragments (K=16 layout)
        f16x4 pa[4], pb[4];
        #pragma unroll
        for (int j = 0; j < 4; ++j) {
            float a0 = __builtin_amdgcn_exp2f(sa[j][0]);
            float a1 = __builtin_amdgcn_exp2f(sa[j][1]);
            float a2 = __builtin_amdgcn_exp2f(sa[j][2]);
            float a3 = __builtin_amdgcn_exp2f(sa[j][3]);
            lpa += (a0 + a1) + (a2 + a3);
            pa[j] = pk4(a0, a1, a2, a3);
            float b0 = __builtin_amdgcn_exp2f(sb[j][0]);
            float b1 = __builtin_amdgcn_exp2f(sb[j][1]);
            float b2 = __builtin_amdgcn_exp2f(sb[j][2]);
            float b3 = __builtin_amdgcn_exp2f(sb[j][3]);
            lpb += (b0 + b1) + (b2 + b3);
            pb[j] = pk4(b0, b1, b2, b3);
        }

        // PV: O[qrow][d] += P * V via 16x16x16 mfma. B-frag lane needs
        // V[t=tc*16+quad*4+e][d=jo*16+l15] = t'-permuted row halfs quad*16+tc*4+e:
        // 2x b128 at chunks (2q)^cs, (2q|1)^cs -> tc pairs {0,1} and {2,3}.
        __builtin_amdgcn_s_setprio(1);
        #pragma unroll
        for (int jo = 0; jo < 4; ++jo) {
            const ushort* vr = &Vb[(jo * 16 + l15) << 6];
            f16x8 v0 = *(const f16x8*)&vr[(((quad << 1) ^ cs) << 3)];
            f16x8 v1 = *(const f16x8*)&vr[((((quad << 1) | 1) ^ cs) << 3)];
            f16x4 vf0 = __builtin_shufflevector(v0, v0, 0, 1, 2, 3);
            f16x4 vf1 = __builtin_shufflevector(v0, v0, 4, 5, 6, 7);
            f16x4 vf2 = __builtin_shufflevector(v1, v1, 0, 1, 2, 3);
            f16x4 vf3 = __builtin_shufflevector(v1, v1, 4, 5, 6, 7);
            ofa[jo] = __builtin_amdgcn_mfma_f32_16x16x16f16(pa[0], vf0, ofa[jo], 0, 0, 0);
            ofa[jo] = __builtin_amdgcn_mfma_f32_16x16x16f16(pa[1], vf1, ofa[jo], 0, 0, 0);
            ofa[jo] = __builtin_amdgcn_mfma_f32_16x16x16f16(pa[2], vf2, ofa[jo], 0, 0, 0);
            ofa[jo] = __builtin_amdgcn_mfma_f32_16x16x16f16(pa[3], vf3, ofa[jo], 0, 0, 0);
            ofb[jo] = __builtin_amdgcn_mfma_f32_16x16x16f16(pb[0], vf0, ofb[jo], 0, 0, 0);
            ofb[jo] = __builtin_amdgcn_mfma_f32_16x16x16f16(pb[1], vf1, ofb[jo], 0, 0, 0);
            ofb[jo] = __builtin_amdgcn_mfma_f32_16x16x16f16(pb[2], vf2, ofb[jo], 0, 0, 0);
            ofb[jo] = __builtin_amdgcn_mfma_f32_16x16x16f16(pb[3], vf3, ofb[jo], 0, 0, 0);
        }
        __builtin_amdgcn_s_setprio(0);

        __syncthreads();            // drains prefetch (overlapped) + guards buf reuse
        cur ^= 1;
    }

    // epilogue: complete row sums across quads (2 shfls), redistribute to C/D layout
    float la = lpa;
    la += __shfl_xor(la, 16, 64);
    la += __shfl_xor(la, 32, 64);
    float lb = lpb;
    lb += __shfl_xor(lb, 16, 64);
    lb += __shfl_xor(lb, 32, 64);
    float ia = 1.f / la, ib = 1.f / lb;
    #pragma unroll
    for (int r = 0; r < 4; ++r) {
        float iar = __shfl(ia, quad * 4 + r, 64);   // inv-sum for qrow quad*4+r
        float ibr = __shfl(ib, quad * 4 + r, 64);
        int row = s0 + w * 16 + quad * 4 + r;
        size_t obase = ((size_t)(b * SS + row)) * HH + (h0 << 6);
        #pragma unroll
        for (int jo = 0; jo < 4; ++jo) {
            attno[obase + jo * 16 + l15]      = f2h(ofa[jo][r] * iar);
            attno[obase + 64 + jo * 16 + l15] = f2h(ofb[jo][r] * ibr);
        }
    }
#undef STAGE
}

extern "C" void kernel_launch(void* const* d_in, const int* in_sizes, int n_in,
                              void* d_out, int out_size, void* d_ws, size_t ws_size,
                              hipStream_t stream) {
    const float* x      = (const float*)d_in[0];
    const float* w_norm = (const float*)d_in[1];
    const float* w_qkv  = (const float*)d_in[2];
    const float* w_out  = (const float*)d_in[3];
    float* out = (float*)d_out;
    char* ws = (char*)d_ws;

    float*  scal  = (float*)(ws + 0);           // [0]=sum|w_qkv|, [1]=sum|w_out|
    float*  rope  = (float*)(ws + 64);          // 2048*64 f32, ends 524352
    char*   xq    = (char*)(ws + 524352);       // 4096*2048 i8, ends 8912960
    float*  xsc   = (float*)(ws + 8912960);     // 4096 f32, ends 8929344
    char*   wq1   = (char*)(ws + 8929344);      // 3072*2048 i8, ends 15220800
    char*   wq2   = (char*)(ws + 15220800);     // 2048*2048 i8, ends 19415104
    ushort* qh    = (ushort*)(ws + 19415104);   // 4096*2048 f16, ends 36192320
    ushort* kh    = (ushort*)(ws + 36192320);   // 4096*512 f16, ends 40386624
    ushort* vT    = (ushort*)(ws + 40386624);   // 2*8*64*2048 f16, ends 44580928
    ushort* attno = (ushort*)(ws + 44580928);   // 4096*2048 f16, ends 61358144

    hipMemsetAsync(scal, 0, 64, stream);
    prep_kernel<<<2816, 256, 0, stream>>>(w_qkv, w_out, scal, rope);
    wquant_kernel<<<2560, 256, 0, stream>>>(w_qkv, w_out, (int*)wq1, (int*)wq2, scal);
    rmsq_kernel<<<MTOK, 256, 0, stream>>>(x, w_norm, (int*)xq, xsc);
    gemm_qkv_kernel<<<dim3(QKVO / 128, MTOK / 128), 256, 0, stream>>>(xq, wq1, xsc, scal + 0,
                                                                      1.0f / 6291456.0f, rope,
                                                                      qh, kh, vT);
    attn_mfma_kernel<<<dim3(SS / 64, NH_ / 2, 2), 256, 0, stream>>>(qh, kh, vT, attno);
    rowq_kernel<<<MTOK, 256, 0, stream>>>(attno, (int*)xq, xsc);
    gemm_i8_kernel<<<dim3(HH / 128, MTOK / 128), 256, 0, stream>>>(xq, wq2, out, xsc, scal + 1,
                                                                   1.0f / 4194304.0f, HH, HH);
}

// Round 9
// 286.883 us; speedup vs baseline: 1.0898x; 1.0898x over previous
//
#include <hip/hip_runtime.h>
#include <math.h>

#define SS   2048
#define HH   2048
#define NH_  32
#define NKV_ 8
#define HD_  64
#define QKVO 3072     // (32 + 2*8) * 64
#define MTOK 4096     // B * S

typedef _Float16 f16x8 __attribute__((ext_vector_type(8)));   // 8 fp16 in 4 VGPRs
typedef _Float16 f16x4 __attribute__((ext_vector_type(4)));   // 4 fp16 in 2 VGPRs
typedef __fp16   fp16x2 __attribute__((ext_vector_type(2))); // cvt_pkrtz return type
typedef float f32x4 __attribute__((ext_vector_type(4)));
typedef int   i32x4 __attribute__((ext_vector_type(4)));      // 16 i8 (A/B frag) or 4 i32 (C/D)

__device__ inline ushort f2h(float f) {
    _Float16 h = (_Float16)f;
    return *(ushort*)&h;
}
__device__ inline f16x4 pk4(float a, float b, float c, float d) {
    union { fp16x2 v2[2]; f16x4 v4; } u;
    u.v2[0] = __builtin_amdgcn_cvt_pkrtz(a, b);
    u.v2[1] = __builtin_amdgcn_cvt_pkrtz(c, d);
    return u.v4;
}
__device__ inline int packi8(float a, float b, float c, float d) {   // values are exact ints
    return ((int)a & 255) | (((int)b & 255) << 8) | (((int)c & 255) << 16) | (((int)d & 255) << 24);
}

__device__ inline void gl_lds16(const void* g, void* l) {
    __builtin_amdgcn_global_load_lds((const __attribute__((address_space(1))) void*)g,
                                     (__attribute__((address_space(3))) void*)l, 16, 0, 0);
}

// ---------------- fused prologue: |w| sums (float4) + rope table ----------------
__global__ __launch_bounds__(256) void prep_kernel(const float* __restrict__ wq,
                                                   const float* __restrict__ wo,
                                                   float* __restrict__ scal,
                                                   float* __restrict__ tab) {
    __shared__ float red[256];
    int bx = blockIdx.x, tid = threadIdx.x;
    if (bx < 2560) {
        const float* src; float* dst; int n4, b0, nb;
        if (bx < 1536) { src = wq; dst = scal + 0; n4 = QKVO * HH / 4; b0 = bx;        nb = 1536; }
        else           { src = wo; dst = scal + 1; n4 = HH * HH / 4;   b0 = bx - 1536; nb = 1024; }
        float acc = 0.f;
        for (int i = b0 * 256 + tid; i < n4; i += nb * 256) {
            float4 v = ((const float4*)src)[i];
            acc += (fabsf(v.x) + fabsf(v.y)) + (fabsf(v.z) + fabsf(v.w));
        }
        red[tid] = acc;
        __syncthreads();
        for (int s = 128; s > 0; s >>= 1) { if (tid < s) red[tid] += red[tid + s]; __syncthreads(); }
        if (tid == 0) atomicAdd(dst, red[0]);
    } else {
        int i = (bx - 2560) * 256 + tid;        // SS*32 threads
        int sp = i >> 5, d = i & 31;
        float inv = (float)pow(10000.0, -(double)d / 32.0);
        float ang = (float)sp * inv;
        tab[sp * 64 + d]      = cosf(ang);
        tab[sp * 64 + 32 + d] = sinf(ang);
    }
}

// ---------------- fused ternary weight quant -> i8 (both weights) ----------------
__global__ __launch_bounds__(256) void wquant_kernel(const float* __restrict__ wq,
                                                     const float* __restrict__ wo,
                                                     int* __restrict__ q1,
                                                     int* __restrict__ q2,
                                                     const float* __restrict__ scal) {
    int bx = blockIdx.x, tid = threadIdx.x;
    const float* src; int* dst; int n4, b0, nb; float mean;
    if (bx < 1536) { src = wq; dst = q1; n4 = QKVO * HH / 4; b0 = bx;        nb = 1536;
                     mean = fmaxf(scal[0] * (1.0f / 6291456.0f), 1e-5f); }
    else           { src = wo; dst = q2; n4 = HH * HH / 4;   b0 = bx - 1536; nb = 1024;
                     mean = fmaxf(scal[1] * (1.0f / 4194304.0f), 1e-5f); }
    float wsc = 1.f / mean;
    for (int i = b0 * 256 + tid; i < n4; i += nb * 256) {
        float4 v = ((const float4*)src)[i];
        dst[i] = packi8(fminf(fmaxf(rintf(v.x * wsc), -1.f), 1.f),
                        fminf(fmaxf(rintf(v.y * wsc), -1.f), 1.f),
                        fminf(fmaxf(rintf(v.z * wsc), -1.f), 1.f),
                        fminf(fmaxf(rintf(v.w * wsc), -1.f), 1.f));
    }
}

// ---------------- RMSNorm + activation quant -> i8 (wave-shuffle reductions, 2 barriers) ----
__global__ __launch_bounds__(256) void rmsq_kernel(const float* __restrict__ x,
                                                   const float* __restrict__ wn,
                                                   int* __restrict__ xq,
                                                   float* __restrict__ xsc) {
    __shared__ float red[8];
    int tid = threadIdx.x;
    int lane = tid & 63, w = tid >> 6;
    const float* xr = x + (size_t)blockIdx.x * HH;
    float4 a = ((const float4*)xr)[tid];
    float4 b = ((const float4*)xr)[tid + 256];
    float s2 = a.x*a.x + a.y*a.y + a.z*a.z + a.w*a.w
             + b.x*b.x + b.y*b.y + b.z*b.z + b.w*b.w;
    #pragma unroll
    for (int o = 32; o > 0; o >>= 1) s2 += __shfl_xor(s2, o, 64);
    if (lane == 0) red[w] = s2;
    __syncthreads();
    float r = rsqrtf((red[0] + red[1] + red[2] + red[3]) * (1.f / HH) + 1e-5f);
    float4 wa = ((const float4*)wn)[tid];
    float4 wb = ((const float4*)wn)[tid + 256];
    float4 na, nb;
    na.x = a.x * r * wa.x; na.y = a.y * r * wa.y; na.z = a.z * r * wa.z; na.w = a.w * r * wa.w;
    nb.x = b.x * r * wb.x; nb.y = b.y * r * wb.y; nb.z = b.z * r * wb.z; nb.w = b.w * r * wb.w;
    float am = fabsf(na.x);
    am = fmaxf(am, fabsf(na.y)); am = fmaxf(am, fabsf(na.z)); am = fmaxf(am, fabsf(na.w));
    am = fmaxf(am, fabsf(nb.x)); am = fmaxf(am, fabsf(nb.y));
    am = fmaxf(am, fabsf(nb.z)); am = fmaxf(am, fabsf(nb.w));
    #pragma unroll
    for (int o = 32; o > 0; o >>= 1) am = fmaxf(am, __shfl_xor(am, o, 64));
    if (lane == 0) red[4 + w] = am;
    __syncthreads();
    float amax = fmaxf(fmaxf(red[4], red[5]), fmaxf(red[6], red[7]));
    amax = fmaxf(amax, 1e-5f);
    float xs = 127.f / amax;
    if (tid == 0) xsc[blockIdx.x] = amax * (1.f / 127.f);
    int* qr = xq + (size_t)blockIdx.x * (HH / 4);
    qr[tid] = packi8(fminf(fmaxf(rintf(na.x * xs), -128.f), 127.f),
                     fminf(fmaxf(rintf(na.y * xs), -128.f), 127.f),
                     fminf(fmaxf(rintf(na.z * xs), -128.f), 127.f),
                     fminf(fmaxf(rintf(na.w * xs), -128.f), 127.f));
    qr[tid + 256] = packi8(fminf(fmaxf(rintf(nb.x * xs), -128.f), 127.f),
                           fminf(fmaxf(rintf(nb.y * xs), -128.f), 127.f),
                           fminf(fmaxf(rintf(nb.z * xs), -128.f), 127.f),
                           fminf(fmaxf(rintf(nb.w * xs), -128.f), 127.f));
}

// ---------------- row absmax quant f16 -> i8 (wave-shuffle reduction, 2 barriers) -----------
__global__ __launch_bounds__(256) void rowq_kernel(const ushort* __restrict__ x,
                                                   int* __restrict__ xq,
                                                   float* __restrict__ xsc) {
    __shared__ float red[4];
    int tid = threadIdx.x;
    int lane = tid & 63, w = tid >> 6;
    const ushort* xr = x + (size_t)blockIdx.x * HH;
    f16x8 v = *(const f16x8*)&xr[tid * 8];
    float f0 = (float)v[0], f1 = (float)v[1], f2 = (float)v[2], f3 = (float)v[3];
    float f4 = (float)v[4], f5 = (float)v[5], f6 = (float)v[6], f7 = (float)v[7];
    float am = fabsf(f0);
    am = fmaxf(am, fabsf(f1)); am = fmaxf(am, fabsf(f2)); am = fmaxf(am, fabsf(f3));
    am = fmaxf(am, fabsf(f4)); am = fmaxf(am, fabsf(f5));
    am = fmaxf(am, fabsf(f6)); am = fmaxf(am, fabsf(f7));
    #pragma unroll
    for (int o = 32; o > 0; o >>= 1) am = fmaxf(am, __shfl_xor(am, o, 64));
    if (lane == 0) red[w] = am;
    __syncthreads();
    float amax = fmaxf(fmaxf(red[0], red[1]), fmaxf(red[2], red[3]));
    amax = fmaxf(amax, 1e-5f);
    float xs = 127.f / amax;
    if (tid == 0) xsc[blockIdx.x] = amax * (1.f / 127.f);
    int* qr = xq + (size_t)blockIdx.x * (HH / 4);
    qr[tid * 2]     = packi8(fminf(fmaxf(rintf(f0 * xs), -128.f), 127.f),
                             fminf(fmaxf(rintf(f1 * xs), -128.f), 127.f),
                             fminf(fmaxf(rintf(f2 * xs), -128.f), 127.f),
                             fminf(fmaxf(rintf(f3 * xs), -128.f), 127.f));
    qr[tid * 2 + 1] = packi8(fminf(fmaxf(rintf(f4 * xs), -128.f), 127.f),
                             fminf(fmaxf(rintf(f5 * xs), -128.f), 127.f),
                             fminf(fmaxf(rintf(f6 * xs), -128.f), 127.f),
                             fminf(fmaxf(rintf(f7 * xs), -128.f), 127.f));
}

// ------- i8 MFMA GEMM, BK=128 swizzled, double-buffered async pipeline (1 barrier/iter) -----
// + XCD-aware block swizzle (bijective: nwg%8==0) and setprio around MFMA clusters.
#define GSTAGE(Abuf, Bbuf, kk) do {                                         \
        _Pragma("unroll")                                                   \
        for (int i_ = 0; i_ < 4; ++i_) {                                    \
            gl_lds16(Arow + (size_t)(i_ * 8) * K + (kk), (Abuf) + (w << 12) + i_ * 1024); \
            gl_lds16(Brow + (size_t)(i_ * 8) * K + (kk), (Bbuf) + (w << 12) + i_ * 1024); \
        }                                                                   \
    } while (0)

#define XCD_SWZ(m0, n0) do {                                                \
        int lb_ = blockIdx.y * gridDim.x + blockIdx.x;                      \
        int nwg_ = gridDim.x * gridDim.y;                                   \
        int swz_ = (lb_ & 7) * (nwg_ >> 3) + (lb_ >> 3);                    \
        m0 = (swz_ / gridDim.x) << 7;                                       \
        n0 = (swz_ % gridDim.x) << 7;                                       \
    } while (0)

__global__ __launch_bounds__(256) void gemm_i8_kernel(const char* __restrict__ A,
                                                      const char* __restrict__ B,
                                                      float* __restrict__ C,
                                                      const float* __restrict__ rsc,
                                                      const float* __restrict__ wsum,
                                                      float inv_n, int N, int K) {
    __shared__ __align__(16) char Alds[2][128 * 128];
    __shared__ __align__(16) char Blds[2][128 * 128];
    int tid = threadIdx.x;
    int lane = tid & 63, w = tid >> 6;
    int quad = lane >> 4, l15 = lane & 15;
    int m0, n0;
    XCD_SWZ(m0, n0);
    int wm = (w >> 1) << 6, wn = (w & 1) << 6;
    int srow = (w << 5) + (lane >> 3);            // + i*8 per staging instr
    int scol = ((lane & 7) ^ (lane >> 3)) << 4;   // XOR swizzle (row&7 == lane>>3)
    const char* Arow = A + (size_t)(m0 + srow) * K + scol;
    const char* Brow = B + (size_t)(n0 + srow) * K + scol;

    i32x4 acc[4][4] = {};
    GSTAGE(Alds[0], Blds[0], 0);
    __syncthreads();
    int buf = 0;
    for (int k0 = 0; k0 < K; k0 += 128) {
        if (k0 + 128 < K) GSTAGE(Alds[buf ^ 1], Blds[buf ^ 1], k0 + 128);
        const char* Ab = Alds[buf];
        const char* Bb = Blds[buf];
        #pragma unroll
        for (int ks = 0; ks < 2; ++ks) {
            i32x4 af[4], bfr[4];
            #pragma unroll
            for (int i = 0; i < 4; ++i) {
                int ra = wm + i * 16 + l15;       // ra&7 == l15&7
                int ca = ((ks * 4 + quad) ^ (l15 & 7)) << 4;
                af[i]  = *(const i32x4*)&Ab[ra * 128 + ca];
                bfr[i] = *(const i32x4*)&Bb[(wn + i * 16 + l15) * 128 + ca];
            }
            __builtin_amdgcn_s_setprio(1);
            #pragma unroll
            for (int i = 0; i < 4; ++i)
                #pragma unroll
                for (int j = 0; j < 4; ++j)
                    acc[i][j] = __builtin_amdgcn_mfma_i32_16x16x64_i8(af[i], bfr[j], acc[i][j], 0, 0, 0);
            __builtin_amdgcn_s_setprio(0);
        }
        __syncthreads();
        buf ^= 1;
    }

    float wsc = fmaxf(wsum[0] * inv_n, 1e-5f);
    #pragma unroll
    for (int i = 0; i < 4; ++i) {
        #pragma unroll
        for (int r = 0; r < 4; ++r) {
            int row = m0 + wm + i * 16 + quad * 4 + r;
            float s = rsc[row] * wsc;
            #pragma unroll
            for (int j = 0; j < 4; ++j) {
                int col = n0 + wn + j * 16 + l15;
                C[(size_t)row * N + col] = (float)acc[i][j][r] * s;
            }
        }
    }
}

// ---------------- QKV i8 GEMM (dbuf pipeline) with fused RoPE + fp16 epilogue ----------------
__global__ __launch_bounds__(256) void gemm_qkv_kernel(const char* __restrict__ A,
                                                       const char* __restrict__ B,
                                                       const float* __restrict__ rsc,
                                                       const float* __restrict__ wsum,
                                                       float inv_n,
                                                       const float* __restrict__ tab,
                                                       ushort* __restrict__ qh,
                                                       ushort* __restrict__ kh,
                                                       ushort* __restrict__ vT) {
    const int K = HH;
    __shared__ __align__(16) char Alds[2][128 * 128];
    __shared__ __align__(16) char Blds[2][128 * 128];
    int tid = threadIdx.x;
    int lane = tid & 63, w = tid >> 6;
    int quad = lane >> 4, l15 = lane & 15;
    int m0, n0;
    XCD_SWZ(m0, n0);
    int wm = (w >> 1) << 6, wn = (w & 1) << 6;
    int srow = (w << 5) + (lane >> 3);
    int scol = ((lane & 7) ^ (lane >> 3)) << 4;
    const char* Arow = A + (size_t)(m0 + srow) * K + scol;
    const char* Brow = B + (size_t)(n0 + srow) * K + scol;

    i32x4 acc[4][4] = {};
    GSTAGE(Alds[0], Blds[0], 0);
    __syncthreads();
    int buf = 0;
    for (int k0 = 0; k0 < K; k0 += 128) {
        if (k0 + 128 < K) GSTAGE(Alds[buf ^ 1], Blds[buf ^ 1], k0 + 128);
        const char* Ab = Alds[buf];
        const char* Bb = Blds[buf];
        #pragma unroll
        for (int ks = 0; ks < 2; ++ks) {
            i32x4 af[4], bfr[4];
            #pragma unroll
            for (int i = 0; i < 4; ++i) {
                int ca = ((ks * 4 + quad) ^ (l15 & 7)) << 4;
                af[i]  = *(const i32x4*)&Ab[(wm + i * 16 + l15) * 128 + ca];
                bfr[i] = *(const i32x4*)&Bb[(wn + i * 16 + l15) * 128 + ca];
            }
            __builtin_amdgcn_s_setprio(1);
            #pragma unroll
            for (int i = 0; i < 4; ++i)
                #pragma unroll
                for (int j = 0; j < 4; ++j)
                    acc[i][j] = __builtin_amdgcn_mfma_i32_16x16x64_i8(af[i], bfr[j], acc[i][j], 0, 0, 0);
            __builtin_amdgcn_s_setprio(0);
        }
        __syncthreads();
        buf ^= 1;
    }

    float wsc = fmaxf(wsum[0] * inv_n, 1e-5f);
    int region = (n0 + wn) >> 6;                 // head index within qkv cols
    if (region < 32) {                           // Q (rope, x0.125, xlog2(e) folded for exp2 softmax)
        const float qscale = 0.125f * 1.44269504088896f;
        #pragma unroll
        for (int i = 0; i < 4; ++i)
            #pragma unroll
            for (int r = 0; r < 4; ++r) {
                int row = m0 + wm + i * 16 + quad * 4 + r;
                float s = rsc[row] * wsc;
                int sp = row & (SS - 1);
                #pragma unroll
                for (int j = 0; j < 2; ++j) {
                    int d = j * 16 + l15;
                    float c = tab[sp * 64 + d], sn = tab[sp * 64 + 32 + d];
                    float xr = (float)acc[i][j][r] * s, xi = (float)acc[i][j + 2][r] * s;
                    qh[(size_t)row * HH + region * 64 + d]      = f2h((xr * c - xi * sn) * qscale);
                    qh[(size_t)row * HH + region * 64 + d + 32] = f2h((xr * sn + xi * c) * qscale);
                }
            }
    } else if (region < 40) {                    // K (rope)
        int kv = region - 32;
        #pragma unroll
        for (int i = 0; i < 4; ++i)
            #pragma unroll
            for (int r = 0; r < 4; ++r) {
                int row = m0 + wm + i * 16 + quad * 4 + r;
                float s = rsc[row] * wsc;
                int sp = row & (SS - 1);
                #pragma unroll
                for (int j = 0; j < 2; ++j) {
                    int d = j * 16 + l15;
                    float c = tab[sp * 64 + d], sn = tab[sp * 64 + 32 + d];
                    float xr = (float)acc[i][j][r] * s, xi = (float)acc[i][j + 2][r] * s;
                    kh[(size_t)row * (NKV_ * 64) + kv * 64 + d]      = f2h(xr * c - xi * sn);
                    kh[(size_t)row * (NKV_ * 64) + kv * 64 + d + 32] = f2h(xr * sn + xi * c);
                }
            }
    } else {                                     // V -> transposed [b][kv][d][t-permuted], packed 4 rows
        // within each 64-half tile, half position t' = quad(t)*16 + tc(t)*4 + e(t)
        // where t = tc*16 + quad*4 + e  (so attn PV reads 32B contiguous per quad)
        int kv = region - 40;
        #pragma unroll
        for (int i = 0; i < 4; ++i) {
            int row0 = m0 + wm + i * 16 + quad * 4;
            int bb = row0 >> 11, sr = row0 & (SS - 1);
            int tp = (sr & ~63) + (((sr >> 2) & 3) << 4) + (((sr >> 4) & 3) << 2);  // e=0 base
            float sc0 = rsc[row0 + 0] * wsc;
            float sc1 = rsc[row0 + 1] * wsc;
            float sc2 = rsc[row0 + 2] * wsc;
            float sc3 = rsc[row0 + 3] * wsc;
            #pragma unroll
            for (int j = 0; j < 4; ++j) {
                int d = j * 16 + l15;
                ushort4 o;
                o.x = f2h((float)acc[i][j][0] * sc0);
                o.y = f2h((float)acc[i][j][1] * sc1);
                o.z = f2h((float)acc[i][j][2] * sc2);
                o.w = f2h((float)acc[i][j][3] * sc3);
                *(ushort4*)&vT[(((size_t)(bb * NKV_ + kv)) * 64 + d) * SS + tp] = o;
            }
        }
    }
}
#undef GSTAGE
#undef XCD_SWZ

// ---------------- MFMA flash attention (R7 proven config: paired q-tiles, 62 us) ----------
// Swapped QK (mfma(K,Q)): lane (quad,l15) holds P[qrow=l15][t] -> row-sum lane-local; P frags
// for K=16 PV from 8 cvt_pkrtz/head, zero shuffles/LDS. vT t-permuted (t'=quad*16+tc*4+e) ->
// V frags 32B contiguous, 2x b128/jo (0-conflict shape). 2 GQA heads/block share K/V.
// Paired q-tiles (31-x, x) -> uniform 33 iters/block; grid 512 = 2/CU; LDS 32KB.
__global__ __launch_bounds__(256, 4) void attn_mfma_kernel(const ushort* __restrict__ qh,
                                                           const ushort* __restrict__ kh,
                                                           const ushort* __restrict__ vT,
                                                           ushort* __restrict__ attno) {
    __shared__ __align__(16) ushort Kl[2][4096];   // [buf][t64 * 64] swizzled
    __shared__ __align__(16) ushort Vl[2][4096];   // [buf][d64 * 64] swizzled (t'-permuted)
    int tid = threadIdx.x;
    int lane = tid & 63, w = tid >> 6;
    int quad = lane >> 4, l15 = lane & 15;
    int x  = blockIdx.x;                             // q-tile pair (31-x, x)
    int h0 = blockIdx.y << 1;                        // heads h0, h0+1 (same kv head, G=4)
    int b  = blockIdx.z;
    int khd = blockIdx.y >> 1;

    int rl = lane >> 3;                              // staging row-within-8
    int cl = ((lane & 7) ^ rl) << 3;                 // pre-swizzled source chunk (halfs)
    const ushort* kbase = kh + ((size_t)b * SS + (w << 4) + rl) * (NKV_ * 64) + (khd << 6) + cl;
    const ushort* vbase = vT + ((((size_t)(b * NKV_ + khd)) << 6) + (w << 4) + rl) * SS + cl;

#define STAGE(bb, tt) do {                                              \
        gl_lds16(kbase + (size_t)(tt) * 512,       &Kl[bb][w << 10]);       \
        gl_lds16(kbase + (size_t)((tt) + 8) * 512, &Kl[bb][(w << 10) + 512]); \
        gl_lds16(vbase + (tt),                     &Vl[bb][w << 10]);       \
        gl_lds16(vbase + 8 * SS + (tt),            &Vl[bb][(w << 10) + 512]); \
    } while (0)

    int cs = l15 & 7;                                // row&7 for frag rows *16+l15
    int cur = 0;                                     // current K/V buffer, carried across phases

    STAGE(0, 0);                                     // phase-0 tile 0

    for (int p = 0; p < 2; ++p) {
        int tq = p ? x : (31 - x);
        int s0 = tq << 6;
        int nt = tq + 1;

        const ushort* qp = qh + ((size_t)(b * SS + s0 + (w << 4) + l15)) * HH + (h0 << 6) + (quad << 3);
        f16x8 qa0 = *(const f16x8*)qp;              // head0 d[0..32)
        f16x8 qa1 = *(const f16x8*)(qp + 32);       // head0 d[32..64)
        f16x8 qb0 = *(const f16x8*)(qp + 64);       // head1
        f16x8 qb1 = *(const f16x8*)(qp + 96);

        if (p == 0) __syncthreads();                 // drains initial stage (phase 1: already drained)

        float lpa = 0.f, lpb = 0.f;
        f32x4 ofa[4] = {};
        f32x4 ofb[4] = {};

        for (int it = 0; it < nt; ++it) {
            // prefetch next tile (or phase 1's first tile) into the spare buffer
            if (it + 1 < nt)      STAGE(cur ^ 1, (it + 1) << 6);
            else if (p == 0)      STAGE(cur ^ 1, 0);

            const ushort* Kb = Kl[cur];
            const ushort* Vb = Vl[cur];

            // swapped QK: sa[j] holds S[t = 16j + 4quad + r][qrow = l15]
            f32x4 sa[4] = {}, sb[4] = {};
            __builtin_amdgcn_s_setprio(1);
            #pragma unroll
            for (int j = 0; j < 4; ++j) {
                const ushort* kr = &Kb[(j * 16 + l15) << 6];
                f16x8 kf0 = *(const f16x8*)&kr[(quad ^ cs) << 3];
                f16x8 kf1 = *(const f16x8*)&kr[((quad | 4) ^ cs) << 3];
                sa[j] = __builtin_amdgcn_mfma_f32_16x16x32_f16(kf0, qa0, sa[j], 0, 0, 0);
                sa[j] = __builtin_amdgcn_mfma_f32_16x16x32_f16(kf1, qa1, sa[j], 0, 0, 0);
                sb[j] = __builtin_amdgcn_mfma_f32_16x16x32_f16(kf0, qb0, sb[j], 0, 0, 0);
                sb[j] = __builtin_amdgcn_mfma_f32_16x16x32_f16(kf1, qb1, sb[j], 0, 0, 0);
            }
            __builtin_amdgcn_s_setprio(0);

            if (it == nt - 1) {             // causal mask: t = 16j+4quad+r vs qrow' = w*16+l15
                int qr = (w << 4) + l15;
                #pragma unroll
                for (int j = 0; j < 4; ++j)
                    #pragma unroll
                    for (int r = 0; r < 4; ++r)
                        if (16 * j + quad * 4 + r > qr) { sa[j][r] = -INFINITY; sb[j][r] = -INFINITY; }
            }

            // exp2 softmax + lane-local row sums + in-register P fragments (K=16 layout)
            f16x4 pa[4], pb[4];
            #pragma unroll
            for (int j = 0; j < 4; ++j) {
                float a0 = __builtin_amdgcn_exp2f(sa[j][0]);
                float a1 = __builtin_amdgcn_exp2f(sa[j][1]);
                float a2 = __builtin_amdgcn_exp2f(sa[j][2]);
                float a3 = __builtin_amdgcn_exp2f(sa[j][3]);
                lpa += (a0 + a1) + (a2 + a3);
                pa[j] = pk4(a0, a1, a2, a3);
                float b0 = __builtin_amdgcn_exp2f(sb[j][0]);
                float b1 = __builtin_amdgcn_exp2f(sb[j][1]);
                float b2 = __builtin_amdgcn_exp2f(sb[j][2]);
                float b3 = __builtin_amdgcn_exp2f(sb[j][3]);
                lpb += (b0 + b1) + (b2 + b3);
                pb[j] = pk4(b0, b1, b2, b3);
            }

            // PV: O[qrow][d] += P * V via 16x16x16 mfma. B-frag lane needs
            // V[t=tc*16+quad*4+e][d=jo*16+l15] = t'-permuted row halfs quad*16+tc*4+e:
            // 2x b128 at chunks (2q)^cs, (2q|1)^cs -> tc pairs {0,1} and {2,3}.
            __builtin_amdgcn_s_setprio(1);
            #pragma unroll
            for (int jo = 0; jo < 4; ++jo) {
                const ushort* vr = &Vb[(jo * 16 + l15) << 6];
                f16x8 v0 = *(const f16x8*)&vr[(((quad << 1) ^ cs) << 3)];
                f16x8 v1 = *(const f16x8*)&vr[((((quad << 1) | 1) ^ cs) << 3)];
                f16x4 vf0 = __builtin_shufflevector(v0, v0, 0, 1, 2, 3);
                f16x4 vf1 = __builtin_shufflevector(v0, v0, 4, 5, 6, 7);
                f16x4 vf2 = __builtin_shufflevector(v1, v1, 0, 1, 2, 3);
                f16x4 vf3 = __builtin_shufflevector(v1, v1, 4, 5, 6, 7);
                ofa[jo] = __builtin_amdgcn_mfma_f32_16x16x16f16(pa[0], vf0, ofa[jo], 0, 0, 0);
                ofa[jo] = __builtin_amdgcn_mfma_f32_16x16x16f16(pa[1], vf1, ofa[jo], 0, 0, 0);
                ofa[jo] = __builtin_amdgcn_mfma_f32_16x16x16f16(pa[2], vf2, ofa[jo], 0, 0, 0);
                ofa[jo] = __builtin_amdgcn_mfma_f32_16x16x16f16(pa[3], vf3, ofa[jo], 0, 0, 0);
                ofb[jo] = __builtin_amdgcn_mfma_f32_16x16x16f16(pb[0], vf0, ofb[jo], 0, 0, 0);
                ofb[jo] = __builtin_amdgcn_mfma_f32_16x16x16f16(pb[1], vf1, ofb[jo], 0, 0, 0);
                ofb[jo] = __builtin_amdgcn_mfma_f32_16x16x16f16(pb[2], vf2, ofb[jo], 0, 0, 0);
                ofb[jo] = __builtin_amdgcn_mfma_f32_16x16x16f16(pb[3], vf3, ofb[jo], 0, 0, 0);
            }
            __builtin_amdgcn_s_setprio(0);

            __syncthreads();            // drains prefetch (overlapped) + guards buf reuse
            cur ^= 1;
        }

        // epilogue: complete row sums across quads (2 shfls), redistribute to C/D layout
        float la = lpa;
        la += __shfl_xor(la, 16, 64);
        la += __shfl_xor(la, 32, 64);
        float lb = lpb;
        lb += __shfl_xor(lb, 16, 64);
        lb += __shfl_xor(lb, 32, 64);
        float ia = 1.f / la, ib = 1.f / lb;
        #pragma unroll
        for (int r = 0; r < 4; ++r) {
            float iar = __shfl(ia, quad * 4 + r, 64);   // inv-sum for qrow quad*4+r
            float ibr = __shfl(ib, quad * 4 + r, 64);
            int row = s0 + w * 16 + quad * 4 + r;
            size_t obase = ((size_t)(b * SS + row)) * HH + (h0 << 6);
            #pragma unroll
            for (int jo = 0; jo < 4; ++jo) {
                attno[obase + jo * 16 + l15]      = f2h(ofa[jo][r] * iar);
                attno[obase + 64 + jo * 16 + l15] = f2h(ofb[jo][r] * ibr);
            }
        }
    }
#undef STAGE
}

extern "C" void kernel_launch(void* const* d_in, const int* in_sizes, int n_in,
                              void* d_out, int out_size, void* d_ws, size_t ws_size,
                              hipStream_t stream) {
    const float* x      = (const float*)d_in[0];
    const float* w_norm = (const float*)d_in[1];
    const float* w_qkv  = (const float*)d_in[2];
    const float* w_out  = (const float*)d_in[3];
    float* out = (float*)d_out;
    char* ws = (char*)d_ws;

    float*  scal  = (float*)(ws + 0);           // [0]=sum|w_qkv|, [1]=sum|w_out|
    float*  rope  = (float*)(ws + 64);          // 2048*64 f32, ends 524352
    char*   xq    = (char*)(ws + 524352);       // 4096*2048 i8, ends 8912960
    float*  xsc   = (float*)(ws + 8912960);     // 4096 f32, ends 8929344
    char*   wq1   = (char*)(ws + 8929344);      // 3072*2048 i8, ends 15220800
    char*   wq2   = (char*)(ws + 15220800);     // 2048*2048 i8, ends 19415104
    ushort* qh    = (ushort*)(ws + 19415104);   // 4096*2048 f16, ends 36192320
    ushort* kh    = (ushort*)(ws + 36192320);   // 4096*512 f16, ends 40386624
    ushort* vT    = (ushort*)(ws + 40386624);   // 2*8*64*2048 f16, ends 44580928
    ushort* attno = (ushort*)(ws + 44580928);   // 4096*2048 f16, ends 61358144

    hipMemsetAsync(scal, 0, 64, stream);
    prep_kernel<<<2816, 256, 0, stream>>>(w_qkv, w_out, scal, rope);
    wquant_kernel<<<2560, 256, 0, stream>>>(w_qkv, w_out, (int*)wq1, (int*)wq2, scal);
    rmsq_kernel<<<MTOK, 256, 0, stream>>>(x, w_norm, (int*)xq, xsc);
    gemm_qkv_kernel<<<dim3(QKVO / 128, MTOK / 128), 256, 0, stream>>>(xq, wq1, xsc, scal + 0,
                                                                      1.0f / 6291456.0f, rope,
                                                                      qh, kh, vT);
    attn_mfma_kernel<<<dim3(SS / 64 / 2, NH_ / 2, 2), 256, 0, stream>>>(qh, kh, vT, attno);
    rowq_kernel<<<MTOK, 256, 0, stream>>>(attno, (int*)xq, xsc);
    gemm_i8_kernel<<<dim3(HH / 128, MTOK / 128), 256, 0, stream>>>(xq, wq2, out, xsc, scal + 1,
                                                                   1.0f / 4194304.0f, HH, HH);
}

// Round 10
// 276.603 us; speedup vs baseline: 1.1303x; 1.0372x over previous
//
#include <hip/hip_runtime.h>
#include <math.h>

#define SS   2048
#define HH   2048
#define NH_  32
#define NKV_ 8
#define HD_  64
#define QKVO 3072     // (32 + 2*8) * 64
#define MTOK 4096     // B * S

typedef _Float16 f16x8 __attribute__((ext_vector_type(8)));   // 8 fp16 in 4 VGPRs
typedef _Float16 f16x4 __attribute__((ext_vector_type(4)));   // 4 fp16 in 2 VGPRs
typedef __fp16   fp16x2 __attribute__((ext_vector_type(2))); // cvt_pkrtz return type
typedef float f32x4 __attribute__((ext_vector_type(4)));
typedef int   i32x4 __attribute__((ext_vector_type(4)));      // 16 i8 (A/B frag) or 4 i32 (C/D)

__device__ inline ushort f2h(float f) {
    _Float16 h = (_Float16)f;
    return *(ushort*)&h;
}
__device__ inline f16x4 pk4(float a, float b, float c, float d) {
    union { fp16x2 v2[2]; f16x4 v4; } u;
    u.v2[0] = __builtin_amdgcn_cvt_pkrtz(a, b);
    u.v2[1] = __builtin_amdgcn_cvt_pkrtz(c, d);
    return u.v4;
}
__device__ inline int packi8(float a, float b, float c, float d) {   // values are exact ints
    return ((int)a & 255) | (((int)b & 255) << 8) | (((int)c & 255) << 16) | (((int)d & 255) << 24);
}

__device__ inline void gl_lds16(const void* g, void* l) {
    __builtin_amdgcn_global_load_lds((const __attribute__((address_space(1))) void*)g,
                                     (__attribute__((address_space(3))) void*)l, 16, 0, 0);
}

// ---------------- fused prologue: |w| sums (float4) + rope table ----------------
__global__ __launch_bounds__(256) void prep_kernel(const float* __restrict__ wq,
                                                   const float* __restrict__ wo,
                                                   float* __restrict__ scal,
                                                   float* __restrict__ tab) {
    __shared__ float red[256];
    int bx = blockIdx.x, tid = threadIdx.x;
    if (bx < 2560) {
        const float* src; float* dst; int n4, b0, nb;
        if (bx < 1536) { src = wq; dst = scal + 0; n4 = QKVO * HH / 4; b0 = bx;        nb = 1536; }
        else           { src = wo; dst = scal + 1; n4 = HH * HH / 4;   b0 = bx - 1536; nb = 1024; }
        float acc = 0.f;
        for (int i = b0 * 256 + tid; i < n4; i += nb * 256) {
            float4 v = ((const float4*)src)[i];
            acc += (fabsf(v.x) + fabsf(v.y)) + (fabsf(v.z) + fabsf(v.w));
        }
        red[tid] = acc;
        __syncthreads();
        for (int s = 128; s > 0; s >>= 1) { if (tid < s) red[tid] += red[tid + s]; __syncthreads(); }
        if (tid == 0) atomicAdd(dst, red[0]);
    } else {
        int i = (bx - 2560) * 256 + tid;        // SS*32 threads
        int sp = i >> 5, d = i & 31;
        float inv = (float)pow(10000.0, -(double)d / 32.0);
        float ang = (float)sp * inv;
        tab[sp * 64 + d]      = cosf(ang);
        tab[sp * 64 + 32 + d] = sinf(ang);
    }
}

// ---------------- fused ternary weight quant -> i8 (both weights) ----------------
__global__ __launch_bounds__(256) void wquant_kernel(const float* __restrict__ wq,
                                                     const float* __restrict__ wo,
                                                     int* __restrict__ q1,
                                                     int* __restrict__ q2,
                                                     const float* __restrict__ scal) {
    int bx = blockIdx.x, tid = threadIdx.x;
    const float* src; int* dst; int n4, b0, nb; float mean;
    if (bx < 1536) { src = wq; dst = q1; n4 = QKVO * HH / 4; b0 = bx;        nb = 1536;
                     mean = fmaxf(scal[0] * (1.0f / 6291456.0f), 1e-5f); }
    else           { src = wo; dst = q2; n4 = HH * HH / 4;   b0 = bx - 1536; nb = 1024;
                     mean = fmaxf(scal[1] * (1.0f / 4194304.0f), 1e-5f); }
    float wsc = 1.f / mean;
    for (int i = b0 * 256 + tid; i < n4; i += nb * 256) {
        float4 v = ((const float4*)src)[i];
        dst[i] = packi8(fminf(fmaxf(rintf(v.x * wsc), -1.f), 1.f),
                        fminf(fmaxf(rintf(v.y * wsc), -1.f), 1.f),
                        fminf(fmaxf(rintf(v.z * wsc), -1.f), 1.f),
                        fminf(fmaxf(rintf(v.w * wsc), -1.f), 1.f));
    }
}

// ---------------- RMSNorm + activation quant -> i8 (wave-shuffle reductions, 2 barriers) ----
__global__ __launch_bounds__(256) void rmsq_kernel(const float* __restrict__ x,
                                                   const float* __restrict__ wn,
                                                   int* __restrict__ xq,
                                                   float* __restrict__ xsc) {
    __shared__ float red[8];
    int tid = threadIdx.x;
    int lane = tid & 63, w = tid >> 6;
    const float* xr = x + (size_t)blockIdx.x * HH;
    float4 a = ((const float4*)xr)[tid];
    float4 b = ((const float4*)xr)[tid + 256];
    float s2 = a.x*a.x + a.y*a.y + a.z*a.z + a.w*a.w
             + b.x*b.x + b.y*b.y + b.z*b.z + b.w*b.w;
    #pragma unroll
    for (int o = 32; o > 0; o >>= 1) s2 += __shfl_xor(s2, o, 64);
    if (lane == 0) red[w] = s2;
    __syncthreads();
    float r = rsqrtf((red[0] + red[1] + red[2] + red[3]) * (1.f / HH) + 1e-5f);
    float4 wa = ((const float4*)wn)[tid];
    float4 wb = ((const float4*)wn)[tid + 256];
    float4 na, nb;
    na.x = a.x * r * wa.x; na.y = a.y * r * wa.y; na.z = a.z * r * wa.z; na.w = a.w * r * wa.w;
    nb.x = b.x * r * wb.x; nb.y = b.y * r * wb.y; nb.z = b.z * r * wb.z; nb.w = b.w * r * wb.w;
    float am = fabsf(na.x);
    am = fmaxf(am, fabsf(na.y)); am = fmaxf(am, fabsf(na.z)); am = fmaxf(am, fabsf(na.w));
    am = fmaxf(am, fabsf(nb.x)); am = fmaxf(am, fabsf(nb.y));
    am = fmaxf(am, fabsf(nb.z)); am = fmaxf(am, fabsf(nb.w));
    #pragma unroll
    for (int o = 32; o > 0; o >>= 1) am = fmaxf(am, __shfl_xor(am, o, 64));
    if (lane == 0) red[4 + w] = am;
    __syncthreads();
    float amax = fmaxf(fmaxf(red[4], red[5]), fmaxf(red[6], red[7]));
    amax = fmaxf(amax, 1e-5f);
    float xs = 127.f / amax;
    if (tid == 0) xsc[blockIdx.x] = amax * (1.f / 127.f);
    int* qr = xq + (size_t)blockIdx.x * (HH / 4);
    qr[tid] = packi8(fminf(fmaxf(rintf(na.x * xs), -128.f), 127.f),
                     fminf(fmaxf(rintf(na.y * xs), -128.f), 127.f),
                     fminf(fmaxf(rintf(na.z * xs), -128.f), 127.f),
                     fminf(fmaxf(rintf(na.w * xs), -128.f), 127.f));
    qr[tid + 256] = packi8(fminf(fmaxf(rintf(nb.x * xs), -128.f), 127.f),
                           fminf(fmaxf(rintf(nb.y * xs), -128.f), 127.f),
                           fminf(fmaxf(rintf(nb.z * xs), -128.f), 127.f),
                           fminf(fmaxf(rintf(nb.w * xs), -128.f), 127.f));
}

// ---------------- row absmax quant f16 -> i8 (wave-shuffle reduction, 2 barriers) -----------
__global__ __launch_bounds__(256) void rowq_kernel(const ushort* __restrict__ x,
                                                   int* __restrict__ xq,
                                                   float* __restrict__ xsc) {
    __shared__ float red[4];
    int tid = threadIdx.x;
    int lane = tid & 63, w = tid >> 6;
    const ushort* xr = x + (size_t)blockIdx.x * HH;
    f16x8 v = *(const f16x8*)&xr[tid * 8];
    float f0 = (float)v[0], f1 = (float)v[1], f2 = (float)v[2], f3 = (float)v[3];
    float f4 = (float)v[4], f5 = (float)v[5], f6 = (float)v[6], f7 = (float)v[7];
    float am = fabsf(f0);
    am = fmaxf(am, fabsf(f1)); am = fmaxf(am, fabsf(f2)); am = fmaxf(am, fabsf(f3));
    am = fmaxf(am, fabsf(f4)); am = fmaxf(am, fabsf(f5));
    am = fmaxf(am, fabsf(f6)); am = fmaxf(am, fabsf(f7));
    #pragma unroll
    for (int o = 32; o > 0; o >>= 1) am = fmaxf(am, __shfl_xor(am, o, 64));
    if (lane == 0) red[w] = am;
    __syncthreads();
    float amax = fmaxf(fmaxf(red[0], red[1]), fmaxf(red[2], red[3]));
    amax = fmaxf(amax, 1e-5f);
    float xs = 127.f / amax;
    if (tid == 0) xsc[blockIdx.x] = amax * (1.f / 127.f);
    int* qr = xq + (size_t)blockIdx.x * (HH / 4);
    qr[tid * 2]     = packi8(fminf(fmaxf(rintf(f0 * xs), -128.f), 127.f),
                             fminf(fmaxf(rintf(f1 * xs), -128.f), 127.f),
                             fminf(fmaxf(rintf(f2 * xs), -128.f), 127.f),
                             fminf(fmaxf(rintf(f3 * xs), -128.f), 127.f));
    qr[tid * 2 + 1] = packi8(fminf(fmaxf(rintf(f4 * xs), -128.f), 127.f),
                             fminf(fmaxf(rintf(f5 * xs), -128.f), 127.f),
                             fminf(fmaxf(rintf(f6 * xs), -128.f), 127.f),
                             fminf(fmaxf(rintf(f7 * xs), -128.f), 127.f));
}

// ------- i8 MFMA GEMM: BK=64 double-buffered (m97-structure), 32KB LDS -> 4 blocks/CU -------
// Rows are 64B = 4 chunks of 16B; logical chunk c stored at position c^(row&3); frag chunk
// for mfma 16x16x64 is quad -> read at (quad^(l15&3)) (same 8-lane/bank-group geometry as the
// proven BK=128 pattern). Per K-step: 4 gl_lds + 8 ds_read_b128 + 16 MFMA, 32 steps.
// + XCD-aware block swizzle and setprio around MFMA clusters.
#define GSTAGE(Abuf, Bbuf, kk) do {                                         \
        _Pragma("unroll")                                                   \
        for (int i_ = 0; i_ < 2; ++i_) {                                    \
            gl_lds16(Arow + (size_t)(i_ * 16) * K + (kk), (Abuf) + (w << 11) + i_ * 1024); \
            gl_lds16(Brow + (size_t)(i_ * 16) * K + (kk), (Bbuf) + (w << 11) + i_ * 1024); \
        }                                                                   \
    } while (0)

#define XCD_SWZ(m0, n0) do {                                                \
        int lb_ = blockIdx.y * gridDim.x + blockIdx.x;                      \
        int nwg_ = gridDim.x * gridDim.y;                                   \
        int swz_ = (lb_ & 7) * (nwg_ >> 3) + (lb_ >> 3);                    \
        m0 = (swz_ / gridDim.x) << 7;                                       \
        n0 = (swz_ % gridDim.x) << 7;                                       \
    } while (0)

__global__ __launch_bounds__(256, 4) void gemm_i8_kernel(const char* __restrict__ A,
                                                         const char* __restrict__ B,
                                                         float* __restrict__ C,
                                                         const float* __restrict__ rsc,
                                                         const float* __restrict__ wsum,
                                                         float inv_n, int N, int K) {
    __shared__ __align__(16) char Alds[2][128 * 64];
    __shared__ __align__(16) char Blds[2][128 * 64];
    int tid = threadIdx.x;
    int lane = tid & 63, w = tid >> 6;
    int quad = lane >> 4, l15 = lane & 15;
    int m0, n0;
    XCD_SWZ(m0, n0);
    int wm = (w >> 1) << 6, wn = (w & 1) << 6;
    int srow = (w << 5) + (lane >> 2);            // + i*16 per staging instr
    int scol = ((lane & 3) ^ ((lane >> 2) & 3)) << 4;   // XOR swizzle (row&3)
    const char* Arow = A + (size_t)(m0 + srow) * K + scol;
    const char* Brow = B + (size_t)(n0 + srow) * K + scol;

    i32x4 acc[4][4] = {};
    GSTAGE(Alds[0], Blds[0], 0);
    __syncthreads();
    int buf = 0;
    int ca = (quad ^ (l15 & 3)) << 4;
    for (int k0 = 0; k0 < K; k0 += 64) {
        if (k0 + 64 < K) GSTAGE(Alds[buf ^ 1], Blds[buf ^ 1], k0 + 64);
        const char* Ab = Alds[buf];
        const char* Bb = Blds[buf];
        i32x4 af[4], bfr[4];
        #pragma unroll
        for (int i = 0; i < 4; ++i) {
            af[i]  = *(const i32x4*)&Ab[(wm + i * 16 + l15) * 64 + ca];
            bfr[i] = *(const i32x4*)&Bb[(wn + i * 16 + l15) * 64 + ca];
        }
        __builtin_amdgcn_s_setprio(1);
        #pragma unroll
        for (int i = 0; i < 4; ++i)
            #pragma unroll
            for (int j = 0; j < 4; ++j)
                acc[i][j] = __builtin_amdgcn_mfma_i32_16x16x64_i8(af[i], bfr[j], acc[i][j], 0, 0, 0);
        __builtin_amdgcn_s_setprio(0);
        __syncthreads();
        buf ^= 1;
    }

    float wsc = fmaxf(wsum[0] * inv_n, 1e-5f);
    #pragma unroll
    for (int i = 0; i < 4; ++i) {
        #pragma unroll
        for (int r = 0; r < 4; ++r) {
            int row = m0 + wm + i * 16 + quad * 4 + r;
            float s = rsc[row] * wsc;
            #pragma unroll
            for (int j = 0; j < 4; ++j) {
                int col = n0 + wn + j * 16 + l15;
                C[(size_t)row * N + col] = (float)acc[i][j][r] * s;
            }
        }
    }
}

// ---------------- QKV i8 GEMM (BK=64 dbuf) with fused RoPE + fp16 epilogue ----------------
__global__ __launch_bounds__(256, 4) void gemm_qkv_kernel(const char* __restrict__ A,
                                                          const char* __restrict__ B,
                                                          const float* __restrict__ rsc,
                                                          const float* __restrict__ wsum,
                                                          float inv_n,
                                                          const float* __restrict__ tab,
                                                          ushort* __restrict__ qh,
                                                          ushort* __restrict__ kh,
                                                          ushort* __restrict__ vT) {
    const int K = HH;
    __shared__ __align__(16) char Alds[2][128 * 64];
    __shared__ __align__(16) char Blds[2][128 * 64];
    int tid = threadIdx.x;
    int lane = tid & 63, w = tid >> 6;
    int quad = lane >> 4, l15 = lane & 15;
    int m0, n0;
    XCD_SWZ(m0, n0);
    int wm = (w >> 1) << 6, wn = (w & 1) << 6;
    int srow = (w << 5) + (lane >> 2);
    int scol = ((lane & 3) ^ ((lane >> 2) & 3)) << 4;
    const char* Arow = A + (size_t)(m0 + srow) * K + scol;
    const char* Brow = B + (size_t)(n0 + srow) * K + scol;

    i32x4 acc[4][4] = {};
    GSTAGE(Alds[0], Blds[0], 0);
    __syncthreads();
    int buf = 0;
    int ca = (quad ^ (l15 & 3)) << 4;
    for (int k0 = 0; k0 < K; k0 += 64) {
        if (k0 + 64 < K) GSTAGE(Alds[buf ^ 1], Blds[buf ^ 1], k0 + 64);
        const char* Ab = Alds[buf];
        const char* Bb = Blds[buf];
        i32x4 af[4], bfr[4];
        #pragma unroll
        for (int i = 0; i < 4; ++i) {
            af[i]  = *(const i32x4*)&Ab[(wm + i * 16 + l15) * 64 + ca];
            bfr[i] = *(const i32x4*)&Bb[(wn + i * 16 + l15) * 64 + ca];
        }
        __builtin_amdgcn_s_setprio(1);
        #pragma unroll
        for (int i = 0; i < 4; ++i)
            #pragma unroll
            for (int j = 0; j < 4; ++j)
                acc[i][j] = __builtin_amdgcn_mfma_i32_16x16x64_i8(af[i], bfr[j], acc[i][j], 0, 0, 0);
        __builtin_amdgcn_s_setprio(0);
        __syncthreads();
        buf ^= 1;
    }

    float wsc = fmaxf(wsum[0] * inv_n, 1e-5f);
    int region = (n0 + wn) >> 6;                 // head index within qkv cols
    if (region < 32) {                           // Q (rope, x0.125, xlog2(e) folded for exp2 softmax)
        const float qscale = 0.125f * 1.44269504088896f;
        #pragma unroll
        for (int i = 0; i < 4; ++i)
            #pragma unroll
            for (int r = 0; r < 4; ++r) {
                int row = m0 + wm + i * 16 + quad * 4 + r;
                float s = rsc[row] * wsc;
                int sp = row & (SS - 1);
                #pragma unroll
                for (int j = 0; j < 2; ++j) {
                    int d = j * 16 + l15;
                    float c = tab[sp * 64 + d], sn = tab[sp * 64 + 32 + d];
                    float xr = (float)acc[i][j][r] * s, xi = (float)acc[i][j + 2][r] * s;
                    qh[(size_t)row * HH + region * 64 + d]      = f2h((xr * c - xi * sn) * qscale);
                    qh[(size_t)row * HH + region * 64 + d + 32] = f2h((xr * sn + xi * c) * qscale);
                }
            }
    } else if (region < 40) {                    // K (rope)
        int kv = region - 32;
        #pragma unroll
        for (int i = 0; i < 4; ++i)
            #pragma unroll
            for (int r = 0; r < 4; ++r) {
                int row = m0 + wm + i * 16 + quad * 4 + r;
                float s = rsc[row] * wsc;
                int sp = row & (SS - 1);
                #pragma unroll
                for (int j = 0; j < 2; ++j) {
                    int d = j * 16 + l15;
                    float c = tab[sp * 64 + d], sn = tab[sp * 64 + 32 + d];
                    float xr = (float)acc[i][j][r] * s, xi = (float)acc[i][j + 2][r] * s;
                    kh[(size_t)row * (NKV_ * 64) + kv * 64 + d]      = f2h(xr * c - xi * sn);
                    kh[(size_t)row * (NKV_ * 64) + kv * 64 + d + 32] = f2h(xr * sn + xi * c);
                }
            }
    } else {                                     // V -> transposed [b][kv][d][t-permuted], packed 4 rows
        // within each 64-half tile, half position t' = quad(t)*16 + tc(t)*4 + e(t)
        // where t = tc*16 + quad*4 + e  (so attn PV reads 32B contiguous per quad)
        int kv = region - 40;
        #pragma unroll
        for (int i = 0; i < 4; ++i) {
            int row0 = m0 + wm + i * 16 + quad * 4;
            int bb = row0 >> 11, sr = row0 & (SS - 1);
            int tp = (sr & ~63) + (((sr >> 2) & 3) << 4) + (((sr >> 4) & 3) << 2);  // e=0 base
            float sc0 = rsc[row0 + 0] * wsc;
            float sc1 = rsc[row0 + 1] * wsc;
            float sc2 = rsc[row0 + 2] * wsc;
            float sc3 = rsc[row0 + 3] * wsc;
            #pragma unroll
            for (int j = 0; j < 4; ++j) {
                int d = j * 16 + l15;
                ushort4 o;
                o.x = f2h((float)acc[i][j][0] * sc0);
                o.y = f2h((float)acc[i][j][1] * sc1);
                o.z = f2h((float)acc[i][j][2] * sc2);
                o.w = f2h((float)acc[i][j][3] * sc3);
                *(ushort4*)&vT[(((size_t)(bb * NKV_ + kv)) * 64 + d) * SS + tp] = o;
            }
        }
    }
}
#undef GSTAGE
#undef XCD_SWZ

// ---------------- MFMA flash attention (R7/R9 proven config: paired q-tiles, 62 us) --------
// Swapped QK (mfma(K,Q)): lane (quad,l15) holds P[qrow=l15][t] -> row-sum lane-local; P frags
// for K=16 PV from 8 cvt_pkrtz/head, zero shuffles/LDS. vT t-permuted (t'=quad*16+tc*4+e) ->
// V frags 32B contiguous, 2x b128/jo (0-conflict shape). 2 GQA heads/block share K/V.
// Paired q-tiles (31-x, x) -> uniform 33 iters/block; grid 512 = 2/CU; LDS 32KB.
__global__ __launch_bounds__(256, 4) void attn_mfma_kernel(const ushort* __restrict__ qh,
                                                           const ushort* __restrict__ kh,
                                                           const ushort* __restrict__ vT,
                                                           ushort* __restrict__ attno) {
    __shared__ __align__(16) ushort Kl[2][4096];   // [buf][t64 * 64] swizzled
    __shared__ __align__(16) ushort Vl[2][4096];   // [buf][d64 * 64] swizzled (t'-permuted)
    int tid = threadIdx.x;
    int lane = tid & 63, w = tid >> 6;
    int quad = lane >> 4, l15 = lane & 15;
    int x  = blockIdx.x;                             // q-tile pair (31-x, x)
    int h0 = blockIdx.y << 1;                        // heads h0, h0+1 (same kv head, G=4)
    int b  = blockIdx.z;
    int khd = blockIdx.y >> 1;

    int rl = lane >> 3;                              // staging row-within-8
    int cl = ((lane & 7) ^ rl) << 3;                 // pre-swizzled source chunk (halfs)
    const ushort* kbase = kh + ((size_t)b * SS + (w << 4) + rl) * (NKV_ * 64) + (khd << 6) + cl;
    const ushort* vbase = vT + ((((size_t)(b * NKV_ + khd)) << 6) + (w << 4) + rl) * SS + cl;

#define STAGE(bb, tt) do {                                              \
        gl_lds16(kbase + (size_t)(tt) * 512,       &Kl[bb][w << 10]);       \
        gl_lds16(kbase + (size_t)((tt) + 8) * 512, &Kl[bb][(w << 10) + 512]); \
        gl_lds16(vbase + (tt),                     &Vl[bb][w << 10]);       \
        gl_lds16(vbase + 8 * SS + (tt),            &Vl[bb][(w << 10) + 512]); \
    } while (0)

    int cs = l15 & 7;                                // row&7 for frag rows *16+l15
    int cur = 0;                                     // current K/V buffer, carried across phases

    STAGE(0, 0);                                     // phase-0 tile 0

    for (int p = 0; p < 2; ++p) {
        int tq = p ? x : (31 - x);
        int s0 = tq << 6;
        int nt = tq + 1;

        const ushort* qp = qh + ((size_t)(b * SS + s0 + (w << 4) + l15)) * HH + (h0 << 6) + (quad << 3);
        f16x8 qa0 = *(const f16x8*)qp;              // head0 d[0..32)
        f16x8 qa1 = *(const f16x8*)(qp + 32);       // head0 d[32..64)
        f16x8 qb0 = *(const f16x8*)(qp + 64);       // head1
        f16x8 qb1 = *(const f16x8*)(qp + 96);

        if (p == 0) __syncthreads();                 // drains initial stage (phase 1: already drained)

        float lpa = 0.f, lpb = 0.f;
        f32x4 ofa[4] = {};
        f32x4 ofb[4] = {};

        for (int it = 0; it < nt; ++it) {
            // prefetch next tile (or phase 1's first tile) into the spare buffer
            if (it + 1 < nt)      STAGE(cur ^ 1, (it + 1) << 6);
            else if (p == 0)      STAGE(cur ^ 1, 0);

            const ushort* Kb = Kl[cur];
            const ushort* Vb = Vl[cur];

            // swapped QK: sa[j] holds S[t = 16j + 4quad + r][qrow = l15]
            f32x4 sa[4] = {}, sb[4] = {};
            __builtin_amdgcn_s_setprio(1);
            #pragma unroll
            for (int j = 0; j < 4; ++j) {
                const ushort* kr = &Kb[(j * 16 + l15) << 6];
                f16x8 kf0 = *(const f16x8*)&kr[(quad ^ cs) << 3];
                f16x8 kf1 = *(const f16x8*)&kr[((quad | 4) ^ cs) << 3];
                sa[j] = __builtin_amdgcn_mfma_f32_16x16x32_f16(kf0, qa0, sa[j], 0, 0, 0);
                sa[j] = __builtin_amdgcn_mfma_f32_16x16x32_f16(kf1, qa1, sa[j], 0, 0, 0);
                sb[j] = __builtin_amdgcn_mfma_f32_16x16x32_f16(kf0, qb0, sb[j], 0, 0, 0);
                sb[j] = __builtin_amdgcn_mfma_f32_16x16x32_f16(kf1, qb1, sb[j], 0, 0, 0);
            }
            __builtin_amdgcn_s_setprio(0);

            if (it == nt - 1) {             // causal mask: t = 16j+4quad+r vs qrow' = w*16+l15
                int qr = (w << 4) + l15;
                #pragma unroll
                for (int j = 0; j < 4; ++j)
                    #pragma unroll
                    for (int r = 0; r < 4; ++r)
                        if (16 * j + quad * 4 + r > qr) { sa[j][r] = -INFINITY; sb[j][r] = -INFINITY; }
            }

            // exp2 softmax + lane-local row sums + in-register P fragments (K=16 layout)
            f16x4 pa[4], pb[4];
            #pragma unroll
            for (int j = 0; j < 4; ++j) {
                float a0 = __builtin_amdgcn_exp2f(sa[j][0]);
                float a1 = __builtin_amdgcn_exp2f(sa[j][1]);
                float a2 = __builtin_amdgcn_exp2f(sa[j][2]);
                float a3 = __builtin_amdgcn_exp2f(sa[j][3]);
                lpa += (a0 + a1) + (a2 + a3);
                pa[j] = pk4(a0, a1, a2, a3);
                float b0 = __builtin_amdgcn_exp2f(sb[j][0]);
                float b1 = __builtin_amdgcn_exp2f(sb[j][1]);
                float b2 = __builtin_amdgcn_exp2f(sb[j][2]);
                float b3 = __builtin_amdgcn_exp2f(sb[j][3]);
                lpb += (b0 + b1) + (b2 + b3);
                pb[j] = pk4(b0, b1, b2, b3);
            }

            // PV: O[qrow][d] += P * V via 16x16x16 mfma. B-frag lane needs
            // V[t=tc*16+quad*4+e][d=jo*16+l15] = t'-permuted row halfs quad*16+tc*4+e:
            // 2x b128 at chunks (2q)^cs, (2q|1)^cs -> tc pairs {0,1} and {2,3}.
            __builtin_amdgcn_s_setprio(1);
            #pragma unroll
            for (int jo = 0; jo < 4; ++jo) {
                const ushort* vr = &Vb[(jo * 16 + l15) << 6];
                f16x8 v0 = *(const f16x8*)&vr[(((quad << 1) ^ cs) << 3)];
                f16x8 v1 = *(const f16x8*)&vr[((((quad << 1) | 1) ^ cs) << 3)];
                f16x4 vf0 = __builtin_shufflevector(v0, v0, 0, 1, 2, 3);
                f16x4 vf1 = __builtin_shufflevector(v0, v0, 4, 5, 6, 7);
                f16x4 vf2 = __builtin_shufflevector(v1, v1, 0, 1, 2, 3);
                f16x4 vf3 = __builtin_shufflevector(v1, v1, 4, 5, 6, 7);
                ofa[jo] = __builtin_amdgcn_mfma_f32_16x16x16f16(pa[0], vf0, ofa[jo], 0, 0, 0);
                ofa[jo] = __builtin_amdgcn_mfma_f32_16x16x16f16(pa[1], vf1, ofa[jo], 0, 0, 0);
                ofa[jo] = __builtin_amdgcn_mfma_f32_16x16x16f16(pa[2], vf2, ofa[jo], 0, 0, 0);
                ofa[jo] = __builtin_amdgcn_mfma_f32_16x16x16f16(pa[3], vf3, ofa[jo], 0, 0, 0);
                ofb[jo] = __builtin_amdgcn_mfma_f32_16x16x16f16(pb[0], vf0, ofb[jo], 0, 0, 0);
                ofb[jo] = __builtin_amdgcn_mfma_f32_16x16x16f16(pb[1], vf1, ofb[jo], 0, 0, 0);
                ofb[jo] = __builtin_amdgcn_mfma_f32_16x16x16f16(pb[2], vf2, ofb[jo], 0, 0, 0);
                ofb[jo] = __builtin_amdgcn_mfma_f32_16x16x16f16(pb[3], vf3, ofb[jo], 0, 0, 0);
            }
            __builtin_amdgcn_s_setprio(0);

            __syncthreads();            // drains prefetch (overlapped) + guards buf reuse
            cur ^= 1;
        }

        // epilogue: complete row sums across quads (2 shfls), redistribute to C/D layout
        float la = lpa;
        la += __shfl_xor(la, 16, 64);
        la += __shfl_xor(la, 32, 64);
        float lb = lpb;
        lb += __shfl_xor(lb, 16, 64);
        lb += __shfl_xor(lb, 32, 64);
        float ia = 1.f / la, ib = 1.f / lb;
        #pragma unroll
        for (int r = 0; r < 4; ++r) {
            float iar = __shfl(ia, quad * 4 + r, 64);   // inv-sum for qrow quad*4+r
            float ibr = __shfl(ib, quad * 4 + r, 64);
            int row = s0 + w * 16 + quad * 4 + r;
            size_t obase = ((size_t)(b * SS + row)) * HH + (h0 << 6);
            #pragma unroll
            for (int jo = 0; jo < 4; ++jo) {
                attno[obase + jo * 16 + l15]      = f2h(ofa[jo][r] * iar);
                attno[obase + 64 + jo * 16 + l15] = f2h(ofb[jo][r] * ibr);
            }
        }
    }
#undef STAGE
}

extern "C" void kernel_launch(void* const* d_in, const int* in_sizes, int n_in,
                              void* d_out, int out_size, void* d_ws, size_t ws_size,
                              hipStream_t stream) {
    const float* x      = (const float*)d_in[0];
    const float* w_norm = (const float*)d_in[1];
    const float* w_qkv  = (const float*)d_in[2];
    const float* w_out  = (const float*)d_in[3];
    float* out = (float*)d_out;
    char* ws = (char*)d_ws;

    float*  scal  = (float*)(ws + 0);           // [0]=sum|w_qkv|, [1]=sum|w_out|
    float*  rope  = (float*)(ws + 64);          // 2048*64 f32, ends 524352
    char*   xq    = (char*)(ws + 524352);       // 4096*2048 i8, ends 8912960
    float*  xsc   = (float*)(ws + 8912960);     // 4096 f32, ends 8929344
    char*   wq1   = (char*)(ws + 8929344);      // 3072*2048 i8, ends 15220800
    char*   wq2   = (char*)(ws + 15220800);     // 2048*2048 i8, ends 19415104
    ushort* qh    = (ushort*)(ws + 19415104);   // 4096*2048 f16, ends 36192320
    ushort* kh    = (ushort*)(ws + 36192320);   // 4096*512 f16, ends 40386624
    ushort* vT    = (ushort*)(ws + 40386624);   // 2*8*64*2048 f16, ends 44580928
    ushort* attno = (ushort*)(ws + 44580928);   // 4096*2048 f16, ends 61358144

    hipMemsetAsync(scal, 0, 64, stream);
    prep_kernel<<<2816, 256, 0, stream>>>(w_qkv, w_out, scal, rope);
    wquant_kernel<<<2560, 256, 0, stream>>>(w_qkv, w_out, (int*)wq1, (int*)wq2, scal);
    rmsq_kernel<<<MTOK, 256, 0, stream>>>(x, w_norm, (int*)xq, xsc);
    gemm_qkv_kernel<<<dim3(QKVO / 128, MTOK / 128), 256, 0, stream>>>(xq, wq1, xsc, scal + 0,
                                                                      1.0f / 6291456.0f, rope,
                                                                      qh, kh, vT);
    attn_mfma_kernel<<<dim3(SS / 64 / 2, NH_ / 2, 2), 256, 0, stream>>>(qh, kh, vT, attno);
    rowq_kernel<<<MTOK, 256, 0, stream>>>(attno, (int*)xq, xsc);
    gemm_i8_kernel<<<dim3(HH / 128, MTOK / 128), 256, 0, stream>>>(xq, wq2, out, xsc, scal + 1,
                                                                   1.0f / 4194304.0f, HH, HH);
}

// Round 11
// 270.601 us; speedup vs baseline: 1.1553x; 1.0222x over previous
//
#include <hip/hip_runtime.h>
#include <math.h>

#define SS   2048
#define HH   2048
#define NH_  32
#define NKV_ 8
#define HD_  64
#define QKVO 3072     // (32 + 2*8) * 64
#define MTOK 4096     // B * S

typedef _Float16 f16x8 __attribute__((ext_vector_type(8)));   // 8 fp16 in 4 VGPRs
typedef _Float16 f16x4 __attribute__((ext_vector_type(4)));   // 4 fp16 in 2 VGPRs
typedef __fp16   fp16x2 __attribute__((ext_vector_type(2))); // cvt_pkrtz return type
typedef float f32x4 __attribute__((ext_vector_type(4)));
typedef int   i32x4 __attribute__((ext_vector_type(4)));      // 16 i8 (A/B frag) or 4 i32 (C/D)

__device__ inline ushort f2h(float f) {
    _Float16 h = (_Float16)f;
    return *(ushort*)&h;
}
__device__ inline f16x4 pk4(float a, float b, float c, float d) {
    union { fp16x2 v2[2]; f16x4 v4; } u;
    u.v2[0] = __builtin_amdgcn_cvt_pkrtz(a, b);
    u.v2[1] = __builtin_amdgcn_cvt_pkrtz(c, d);
    return u.v4;
}
__device__ inline int packi8(float a, float b, float c, float d) {   // values are exact ints
    return ((int)a & 255) | (((int)b & 255) << 8) | (((int)c & 255) << 16) | (((int)d & 255) << 24);
}

__device__ inline void gl_lds16(const void* g, void* l) {
    __builtin_amdgcn_global_load_lds((const __attribute__((address_space(1))) void*)g,
                                     (__attribute__((address_space(3))) void*)l, 16, 0, 0);
}

// ---------------- fused prologue: |w| sums (float4) + rope table ----------------
__global__ __launch_bounds__(256) void prep_kernel(const float* __restrict__ wq,
                                                   const float* __restrict__ wo,
                                                   float* __restrict__ scal,
                                                   float* __restrict__ tab) {
    __shared__ float red[256];
    int bx = blockIdx.x, tid = threadIdx.x;
    if (bx < 2560) {
        const float* src; float* dst; int n4, b0, nb;
        if (bx < 1536) { src = wq; dst = scal + 0; n4 = QKVO * HH / 4; b0 = bx;        nb = 1536; }
        else           { src = wo; dst = scal + 1; n4 = HH * HH / 4;   b0 = bx - 1536; nb = 1024; }
        float acc = 0.f;
        for (int i = b0 * 256 + tid; i < n4; i += nb * 256) {
            float4 v = ((const float4*)src)[i];
            acc += (fabsf(v.x) + fabsf(v.y)) + (fabsf(v.z) + fabsf(v.w));
        }
        red[tid] = acc;
        __syncthreads();
        for (int s = 128; s > 0; s >>= 1) { if (tid < s) red[tid] += red[tid + s]; __syncthreads(); }
        if (tid == 0) atomicAdd(dst, red[0]);
    } else {
        int i = (bx - 2560) * 256 + tid;        // SS*32 threads
        int sp = i >> 5, d = i & 31;
        float inv = (float)pow(10000.0, -(double)d / 32.0);
        float ang = (float)sp * inv;
        tab[sp * 64 + d]      = cosf(ang);
        tab[sp * 64 + 32 + d] = sinf(ang);
    }
}

// ---------------- fused ternary weight quant -> i8 (both weights) ----------------
__global__ __launch_bounds__(256) void wquant_kernel(const float* __restrict__ wq,
                                                     const float* __restrict__ wo,
                                                     int* __restrict__ q1,
                                                     int* __restrict__ q2,
                                                     const float* __restrict__ scal) {
    int bx = blockIdx.x, tid = threadIdx.x;
    const float* src; int* dst; int n4, b0, nb; float mean;
    if (bx < 1536) { src = wq; dst = q1; n4 = QKVO * HH / 4; b0 = bx;        nb = 1536;
                     mean = fmaxf(scal[0] * (1.0f / 6291456.0f), 1e-5f); }
    else           { src = wo; dst = q2; n4 = HH * HH / 4;   b0 = bx - 1536; nb = 1024;
                     mean = fmaxf(scal[1] * (1.0f / 4194304.0f), 1e-5f); }
    float wsc = 1.f / mean;
    for (int i = b0 * 256 + tid; i < n4; i += nb * 256) {
        float4 v = ((const float4*)src)[i];
        dst[i] = packi8(fminf(fmaxf(rintf(v.x * wsc), -1.f), 1.f),
                        fminf(fmaxf(rintf(v.y * wsc), -1.f), 1.f),
                        fminf(fmaxf(rintf(v.z * wsc), -1.f), 1.f),
                        fminf(fmaxf(rintf(v.w * wsc), -1.f), 1.f));
    }
}

// ---------------- RMSNorm + activation quant -> i8 (wave-shuffle reductions, 2 barriers) ----
__global__ __launch_bounds__(256) void rmsq_kernel(const float* __restrict__ x,
                                                   const float* __restrict__ wn,
                                                   int* __restrict__ xq,
                                                   float* __restrict__ xsc) {
    __shared__ float red[8];
    int tid = threadIdx.x;
    int lane = tid & 63, w = tid >> 6;
    const float* xr = x + (size_t)blockIdx.x * HH;
    float4 a = ((const float4*)xr)[tid];
    float4 b = ((const float4*)xr)[tid + 256];
    float s2 = a.x*a.x + a.y*a.y + a.z*a.z + a.w*a.w
             + b.x*b.x + b.y*b.y + b.z*b.z + b.w*b.w;
    #pragma unroll
    for (int o = 32; o > 0; o >>= 1) s2 += __shfl_xor(s2, o, 64);
    if (lane == 0) red[w] = s2;
    __syncthreads();
    float r = rsqrtf((red[0] + red[1] + red[2] + red[3]) * (1.f / HH) + 1e-5f);
    float4 wa = ((const float4*)wn)[tid];
    float4 wb = ((const float4*)wn)[tid + 256];
    float4 na, nb;
    na.x = a.x * r * wa.x; na.y = a.y * r * wa.y; na.z = a.z * r * wa.z; na.w = a.w * r * wa.w;
    nb.x = b.x * r * wb.x; nb.y = b.y * r * wb.y; nb.z = b.z * r * wb.z; nb.w = b.w * r * wb.w;
    float am = fabsf(na.x);
    am = fmaxf(am, fabsf(na.y)); am = fmaxf(am, fabsf(na.z)); am = fmaxf(am, fabsf(na.w));
    am = fmaxf(am, fabsf(nb.x)); am = fmaxf(am, fabsf(nb.y));
    am = fmaxf(am, fabsf(nb.z)); am = fmaxf(am, fabsf(nb.w));
    #pragma unroll
    for (int o = 32; o > 0; o >>= 1) am = fmaxf(am, __shfl_xor(am, o, 64));
    if (lane == 0) red[4 + w] = am;
    __syncthreads();
    float amax = fmaxf(fmaxf(red[4], red[5]), fmaxf(red[6], red[7]));
    amax = fmaxf(amax, 1e-5f);
    float xs = 127.f / amax;
    if (tid == 0) xsc[blockIdx.x] = amax * (1.f / 127.f);
    int* qr = xq + (size_t)blockIdx.x * (HH / 4);
    qr[tid] = packi8(fminf(fmaxf(rintf(na.x * xs), -128.f), 127.f),
                     fminf(fmaxf(rintf(na.y * xs), -128.f), 127.f),
                     fminf(fmaxf(rintf(na.z * xs), -128.f), 127.f),
                     fminf(fmaxf(rintf(na.w * xs), -128.f), 127.f));
    qr[tid + 256] = packi8(fminf(fmaxf(rintf(nb.x * xs), -128.f), 127.f),
                           fminf(fmaxf(rintf(nb.y * xs), -128.f), 127.f),
                           fminf(fmaxf(rintf(nb.z * xs), -128.f), 127.f),
                           fminf(fmaxf(rintf(nb.w * xs), -128.f), 127.f));
}

// ---------------- row absmax quant f16 -> i8 (wave-shuffle reduction, 2 barriers) -----------
__global__ __launch_bounds__(256) void rowq_kernel(const ushort* __restrict__ x,
                                                   int* __restrict__ xq,
                                                   float* __restrict__ xsc) {
    __shared__ float red[4];
    int tid = threadIdx.x;
    int lane = tid & 63, w = tid >> 6;
    const ushort* xr = x + (size_t)blockIdx.x * HH;
    f16x8 v = *(const f16x8*)&xr[tid * 8];
    float f0 = (float)v[0], f1 = (float)v[1], f2 = (float)v[2], f3 = (float)v[3];
    float f4 = (float)v[4], f5 = (float)v[5], f6 = (float)v[6], f7 = (float)v[7];
    float am = fabsf(f0);
    am = fmaxf(am, fabsf(f1)); am = fmaxf(am, fabsf(f2)); am = fmaxf(am, fabsf(f3));
    am = fmaxf(am, fabsf(f4)); am = fmaxf(am, fabsf(f5));
    am = fmaxf(am, fabsf(f6)); am = fmaxf(am, fabsf(f7));
    #pragma unroll
    for (int o = 32; o > 0; o >>= 1) am = fmaxf(am, __shfl_xor(am, o, 64));
    if (lane == 0) red[w] = am;
    __syncthreads();
    float amax = fmaxf(fmaxf(red[0], red[1]), fmaxf(red[2], red[3]));
    amax = fmaxf(amax, 1e-5f);
    float xs = 127.f / amax;
    if (tid == 0) xsc[blockIdx.x] = amax * (1.f / 127.f);
    int* qr = xq + (size_t)blockIdx.x * (HH / 4);
    qr[tid * 2]     = packi8(fminf(fmaxf(rintf(f0 * xs), -128.f), 127.f),
                             fminf(fmaxf(rintf(f1 * xs), -128.f), 127.f),
                             fminf(fmaxf(rintf(f2 * xs), -128.f), 127.f),
                             fminf(fmaxf(rintf(f3 * xs), -128.f), 127.f));
    qr[tid * 2 + 1] = packi8(fminf(fmaxf(rintf(f4 * xs), -128.f), 127.f),
                             fminf(fmaxf(rintf(f5 * xs), -128.f), 127.f),
                             fminf(fmaxf(rintf(f6 * xs), -128.f), 127.f),
                             fminf(fmaxf(rintf(f7 * xs), -128.f), 127.f));
}

// ------- i8 MFMA GEMM: BK=64 double-buffered (m97-structure), 32KB LDS -> 4 blocks/CU -------
// Rows are 64B = 4 chunks of 16B; logical chunk c stored at position c^(row&3); frag chunk
// for mfma 16x16x64 is quad -> read at (quad^(l15&3)). Per K-step: 4 gl_lds + 8 ds_read_b128
// + 16 MFMA, 32 steps. + XCD-aware block swizzle and setprio around MFMA clusters.
#define GSTAGE(Abuf, Bbuf, kk) do {                                         \
        _Pragma("unroll")                                                   \
        for (int i_ = 0; i_ < 2; ++i_) {                                    \
            gl_lds16(Arow + (size_t)(i_ * 16) * K + (kk), (Abuf) + (w << 11) + i_ * 1024); \
            gl_lds16(Brow + (size_t)(i_ * 16) * K + (kk), (Bbuf) + (w << 11) + i_ * 1024); \
        }                                                                   \
    } while (0)

#define XCD_SWZ(m0, n0) do {                                                \
        int lb_ = blockIdx.y * gridDim.x + blockIdx.x;                      \
        int nwg_ = gridDim.x * gridDim.y;                                   \
        int swz_ = (lb_ & 7) * (nwg_ >> 3) + (lb_ >> 3);                    \
        m0 = (swz_ / gridDim.x) << 7;                                       \
        n0 = (swz_ % gridDim.x) << 7;                                       \
    } while (0)

__global__ __launch_bounds__(256, 4) void gemm_i8_kernel(const char* __restrict__ A,
                                                         const char* __restrict__ B,
                                                         float* __restrict__ C,
                                                         const float* __restrict__ rsc,
                                                         const float* __restrict__ wsum,
                                                         float inv_n, int N, int K) {
    __shared__ __align__(16) char Alds[2][128 * 64];
    __shared__ __align__(16) char Blds[2][128 * 64];
    int tid = threadIdx.x;
    int lane = tid & 63, w = tid >> 6;
    int quad = lane >> 4, l15 = lane & 15;
    int m0, n0;
    XCD_SWZ(m0, n0);
    int wm = (w >> 1) << 6, wn = (w & 1) << 6;
    int srow = (w << 5) + (lane >> 2);            // + i*16 per staging instr
    int scol = ((lane & 3) ^ ((lane >> 2) & 3)) << 4;   // XOR swizzle (row&3)
    const char* Arow = A + (size_t)(m0 + srow) * K + scol;
    const char* Brow = B + (size_t)(n0 + srow) * K + scol;

    i32x4 acc[4][4] = {};
    GSTAGE(Alds[0], Blds[0], 0);
    __syncthreads();
    int buf = 0;
    int ca = (quad ^ (l15 & 3)) << 4;
    for (int k0 = 0; k0 < K; k0 += 64) {
        if (k0 + 64 < K) GSTAGE(Alds[buf ^ 1], Blds[buf ^ 1], k0 + 64);
        const char* Ab = Alds[buf];
        const char* Bb = Blds[buf];
        i32x4 af[4], bfr[4];
        #pragma unroll
        for (int i = 0; i < 4; ++i) {
            af[i]  = *(const i32x4*)&Ab[(wm + i * 16 + l15) * 64 + ca];
            bfr[i] = *(const i32x4*)&Bb[(wn + i * 16 + l15) * 64 + ca];
        }
        __builtin_amdgcn_s_setprio(1);
        #pragma unroll
        for (int i = 0; i < 4; ++i)
            #pragma unroll
            for (int j = 0; j < 4; ++j)
                acc[i][j] = __builtin_amdgcn_mfma_i32_16x16x64_i8(af[i], bfr[j], acc[i][j], 0, 0, 0);
        __builtin_amdgcn_s_setprio(0);
        __syncthreads();
        buf ^= 1;
    }

    float wsc = fmaxf(wsum[0] * inv_n, 1e-5f);
    #pragma unroll
    for (int i = 0; i < 4; ++i) {
        #pragma unroll
        for (int r = 0; r < 4; ++r) {
            int row = m0 + wm + i * 16 + quad * 4 + r;
            float s = rsc[row] * wsc;
            #pragma unroll
            for (int j = 0; j < 4; ++j) {
                int col = n0 + wn + j * 16 + l15;
                C[(size_t)row * N + col] = (float)acc[i][j][r] * s;
            }
        }
    }
}

// ---------------- QKV i8 GEMM (BK=64 dbuf) with fused RoPE + fp16 epilogue ----------------
__global__ __launch_bounds__(256, 4) void gemm_qkv_kernel(const char* __restrict__ A,
                                                          const char* __restrict__ B,
                                                          const float* __restrict__ rsc,
                                                          const float* __restrict__ wsum,
                                                          float inv_n,
                                                          const float* __restrict__ tab,
                                                          ushort* __restrict__ qh,
                                                          ushort* __restrict__ kh,
                                                          ushort* __restrict__ vT) {
    const int K = HH;
    __shared__ __align__(16) char Alds[2][128 * 64];
    __shared__ __align__(16) char Blds[2][128 * 64];
    int tid = threadIdx.x;
    int lane = tid & 63, w = tid >> 6;
    int quad = lane >> 4, l15 = lane & 15;
    int m0, n0;
    XCD_SWZ(m0, n0);
    int wm = (w >> 1) << 6, wn = (w & 1) << 6;
    int srow = (w << 5) + (lane >> 2);
    int scol = ((lane & 3) ^ ((lane >> 2) & 3)) << 4;
    const char* Arow = A + (size_t)(m0 + srow) * K + scol;
    const char* Brow = B + (size_t)(n0 + srow) * K + scol;

    i32x4 acc[4][4] = {};
    GSTAGE(Alds[0], Blds[0], 0);
    __syncthreads();
    int buf = 0;
    int ca = (quad ^ (l15 & 3)) << 4;
    for (int k0 = 0; k0 < K; k0 += 64) {
        if (k0 + 64 < K) GSTAGE(Alds[buf ^ 1], Blds[buf ^ 1], k0 + 64);
        const char* Ab = Alds[buf];
        const char* Bb = Blds[buf];
        i32x4 af[4], bfr[4];
        #pragma unroll
        for (int i = 0; i < 4; ++i) {
            af[i]  = *(const i32x4*)&Ab[(wm + i * 16 + l15) * 64 + ca];
            bfr[i] = *(const i32x4*)&Bb[(wn + i * 16 + l15) * 64 + ca];
        }
        __builtin_amdgcn_s_setprio(1);
        #pragma unroll
        for (int i = 0; i < 4; ++i)
            #pragma unroll
            for (int j = 0; j < 4; ++j)
                acc[i][j] = __builtin_amdgcn_mfma_i32_16x16x64_i8(af[i], bfr[j], acc[i][j], 0, 0, 0);
        __builtin_amdgcn_s_setprio(0);
        __syncthreads();
        buf ^= 1;
    }

    float wsc = fmaxf(wsum[0] * inv_n, 1e-5f);
    int region = (n0 + wn) >> 6;                 // head index within qkv cols
    if (region < 32) {                           // Q (rope, x0.125, xlog2(e) folded for exp2 softmax)
        const float qscale = 0.125f * 1.44269504088896f;
        #pragma unroll
        for (int i = 0; i < 4; ++i)
            #pragma unroll
            for (int r = 0; r < 4; ++r) {
                int row = m0 + wm + i * 16 + quad * 4 + r;
                float s = rsc[row] * wsc;
                int sp = row & (SS - 1);
                #pragma unroll
                for (int j = 0; j < 2; ++j) {
                    int d = j * 16 + l15;
                    float c = tab[sp * 64 + d], sn = tab[sp * 64 + 32 + d];
                    float xr = (float)acc[i][j][r] * s, xi = (float)acc[i][j + 2][r] * s;
                    qh[(size_t)row * HH + region * 64 + d]      = f2h((xr * c - xi * sn) * qscale);
                    qh[(size_t)row * HH + region * 64 + d + 32] = f2h((xr * sn + xi * c) * qscale);
                }
            }
    } else if (region < 40) {                    // K (rope)
        int kv = region - 32;
        #pragma unroll
        for (int i = 0; i < 4; ++i)
            #pragma unroll
            for (int r = 0; r < 4; ++r) {
                int row = m0 + wm + i * 16 + quad * 4 + r;
                float s = rsc[row] * wsc;
                int sp = row & (SS - 1);
                #pragma unroll
                for (int j = 0; j < 2; ++j) {
                    int d = j * 16 + l15;
                    float c = tab[sp * 64 + d], sn = tab[sp * 64 + 32 + d];
                    float xr = (float)acc[i][j][r] * s, xi = (float)acc[i][j + 2][r] * s;
                    kh[(size_t)row * (NKV_ * 64) + kv * 64 + d]      = f2h(xr * c - xi * sn);
                    kh[(size_t)row * (NKV_ * 64) + kv * 64 + d + 32] = f2h(xr * sn + xi * c);
                }
            }
    } else {                                     // V -> transposed [b][kv][d][t-permuted], packed 4 rows
        // within each 64-half tile, half position t' = quad(t)*16 + tc(t)*4 + e(t)
        // where t = tc*16 + quad*4 + e  (so attn PV reads 32B contiguous per quad)
        int kv = region - 40;
        #pragma unroll
        for (int i = 0; i < 4; ++i) {
            int row0 = m0 + wm + i * 16 + quad * 4;
            int bb = row0 >> 11, sr = row0 & (SS - 1);
            int tp = (sr & ~63) + (((sr >> 2) & 3) << 4) + (((sr >> 4) & 3) << 2);  // e=0 base
            float sc0 = rsc[row0 + 0] * wsc;
            float sc1 = rsc[row0 + 1] * wsc;
            float sc2 = rsc[row0 + 2] * wsc;
            float sc3 = rsc[row0 + 3] * wsc;
            #pragma unroll
            for (int j = 0; j < 4; ++j) {
                int d = j * 16 + l15;
                ushort4 o;
                o.x = f2h((float)acc[i][j][0] * sc0);
                o.y = f2h((float)acc[i][j][1] * sc1);
                o.z = f2h((float)acc[i][j][2] * sc2);
                o.w = f2h((float)acc[i][j][3] * sc3);
                *(ushort4*)&vT[(((size_t)(bb * NKV_ + kv)) * 64 + d) * SS + tp] = o;
            }
        }
    }
}
#undef GSTAGE
#undef XCD_SWZ

// ---------------- MFMA flash attention: KVBLK=128 chunks (2 sub-tiles per barrier) --------
// R9 structure + chunking: per chunk, stage TWO 64-tiles (8 gl_lds) and compute both with no
// barrier between -> sub-1's ds_reads overlap sub-0's MFMA/exp chain; barriers 33 -> 17 per
// phase-pair. LDS 64KB (2 buf x 16KB K + V) = 2 blocks/CU, matching grid 512. Swapped QK,
// in-register softmax (exp2, log2e folded in Q), t'-permuted vT, paired q-tiles (31-x, x).
__global__ __launch_bounds__(256, 2) void attn_mfma_kernel(const ushort* __restrict__ qh,
                                                           const ushort* __restrict__ kh,
                                                           const ushort* __restrict__ vT,
                                                           ushort* __restrict__ attno) {
    __shared__ __align__(16) ushort Kl[2][8192];   // [buf][2 sub-tiles][t64 * 64] swizzled
    __shared__ __align__(16) ushort Vl[2][8192];   // [buf][2 sub-tiles][d64 * 64] (t'-permuted)
    int tid = threadIdx.x;
    int lane = tid & 63, w = tid >> 6;
    int quad = lane >> 4, l15 = lane & 15;
    int x  = blockIdx.x;                             // q-tile pair (31-x, x)
    int h0 = blockIdx.y << 1;                        // heads h0, h0+1 (same kv head, G=4)
    int b  = blockIdx.z;
    int khd = blockIdx.y >> 1;

    int rl = lane >> 3;                              // staging row-within-8
    int cl = ((lane & 7) ^ rl) << 3;                 // pre-swizzled source chunk (halfs)
    const ushort* kbase = kh + ((size_t)b * SS + (w << 4) + rl) * (NKV_ * 64) + (khd << 6) + cl;
    const ushort* vbase = vT + ((((size_t)(b * NKV_ + khd)) << 6) + (w << 4) + rl) * SS + cl;

// stage one 64-tile (rows r0..r0+63) into sub-slot `half` of buffer bb
#define STAGE1(bb, half, r0) do {                                                     \
        gl_lds16(kbase + (size_t)(r0) * 512,       &Kl[bb][((half) << 12) + (w << 10)]);       \
        gl_lds16(kbase + (size_t)((r0) + 8) * 512, &Kl[bb][((half) << 12) + (w << 10) + 512]); \
        gl_lds16(vbase + (r0),                     &Vl[bb][((half) << 12) + (w << 10)]);       \
        gl_lds16(vbase + 8 * SS + (r0),            &Vl[bb][((half) << 12) + (w << 10) + 512]); \
    } while (0)

    int cs = l15 & 7;                                // row&7 for frag rows *16+l15
    int cur = 0;                                     // current K/V buffer, carried across phases
    int nt1 = x + 1;                                 // phase-1 tile count (for cross-phase prefetch)

    {   // prologue: stage phase-0 chunk 0 (tiles 0,1)
        int nt0 = 32 - x;
        STAGE1(0, 0, 0);
        if (nt0 > 1) STAGE1(0, 1, 64);
    }

    for (int p = 0; p < 2; ++p) {
        int tq = p ? x : (31 - x);
        int s0 = tq << 6;
        int nt = tq + 1;
        int nch = (nt + 1) >> 1;

        const ushort* qp = qh + ((size_t)(b * SS + s0 + (w << 4) + l15)) * HH + (h0 << 6) + (quad << 3);
        f16x8 qa0 = *(const f16x8*)qp;              // head0 d[0..32)
        f16x8 qa1 = *(const f16x8*)(qp + 32);       // head0 d[32..64)
        f16x8 qb0 = *(const f16x8*)(qp + 64);       // head1
        f16x8 qb1 = *(const f16x8*)(qp + 96);

        if (p == 0) __syncthreads();                 // drains prologue stage (phase 1: already drained)

        float lpa = 0.f, lpb = 0.f;
        f32x4 ofa[4] = {};
        f32x4 ofb[4] = {};

        for (int c = 0; c < nch; ++c) {
            // prefetch next chunk (or phase 1's chunk 0) into the spare buffer
            if (c + 1 < nch) {
                int r0 = (c + 1) << 7;               // tile 2(c+1) row offset
                STAGE1(cur ^ 1, 0, r0);
                if (((c + 1) << 1) + 1 < nt) STAGE1(cur ^ 1, 1, r0 + 64);
            } else if (p == 0) {
                STAGE1(cur ^ 1, 0, 0);
                if (nt1 > 1) STAGE1(cur ^ 1, 1, 64);
            }

            #pragma unroll
            for (int sub = 0; sub < 2; ++sub) {
                int t = (c << 1) + sub;
                if (t < nt) {
                    const ushort* Kb = &Kl[cur][sub << 12];
                    const ushort* Vb = &Vl[cur][sub << 12];

                    // swapped QK: sa[j] holds S[t = 16j + 4quad + r][qrow = l15]
                    f32x4 sa[4] = {}, sb[4] = {};
                    __builtin_amdgcn_s_setprio(1);
                    #pragma unroll
                    for (int j = 0; j < 4; ++j) {
                        const ushort* kr = &Kb[(j * 16 + l15) << 6];
                        f16x8 kf0 = *(const f16x8*)&kr[(quad ^ cs) << 3];
                        f16x8 kf1 = *(const f16x8*)&kr[((quad | 4) ^ cs) << 3];
                        sa[j] = __builtin_amdgcn_mfma_f32_16x16x32_f16(kf0, qa0, sa[j], 0, 0, 0);
                        sa[j] = __builtin_amdgcn_mfma_f32_16x16x32_f16(kf1, qa1, sa[j], 0, 0, 0);
                        sb[j] = __builtin_amdgcn_mfma_f32_16x16x32_f16(kf0, qb0, sb[j], 0, 0, 0);
                        sb[j] = __builtin_amdgcn_mfma_f32_16x16x32_f16(kf1, qb1, sb[j], 0, 0, 0);
                    }
                    __builtin_amdgcn_s_setprio(0);

                    if (t == nt - 1) {      // causal mask, diagonal tile only
                        int qr = (w << 4) + l15;
                        #pragma unroll
                        for (int j = 0; j < 4; ++j)
                            #pragma unroll
                            for (int r = 0; r < 4; ++r)
                                if (16 * j + quad * 4 + r > qr) { sa[j][r] = -INFINITY; sb[j][r] = -INFINITY; }
                    }

                    // exp2 softmax + lane-local row sums + in-register P fragments
                    f16x4 pa[4], pb[4];
                    #pragma unroll
                    for (int j = 0; j < 4; ++j) {
                        float a0 = __builtin_amdgcn_exp2f(sa[j][0]);
                        float a1 = __builtin_amdgcn_exp2f(sa[j][1]);
                        float a2 = __builtin_amdgcn_exp2f(sa[j][2]);
                        float a3 = __builtin_amdgcn_exp2f(sa[j][3]);
                        lpa += (a0 + a1) + (a2 + a3);
                        pa[j] = pk4(a0, a1, a2, a3);
                        float b0 = __builtin_amdgcn_exp2f(sb[j][0]);
                        float b1 = __builtin_amdgcn_exp2f(sb[j][1]);
                        float b2 = __builtin_amdgcn_exp2f(sb[j][2]);
                        float b3 = __builtin_amdgcn_exp2f(sb[j][3]);
                        lpb += (b0 + b1) + (b2 + b3);
                        pb[j] = pk4(b0, b1, b2, b3);
                    }

                    // PV: O[qrow][d] += P * V via 16x16x16 mfma; t'-permuted vT gives each
                    // lane 32B contiguous -> 2x b128 at chunks (2q)^cs, (2q|1)^cs.
                    __builtin_amdgcn_s_setprio(1);
                    #pragma unroll
                    for (int jo = 0; jo < 4; ++jo) {
                        const ushort* vr = &Vb[(jo * 16 + l15) << 6];
                        f16x8 v0 = *(const f16x8*)&vr[(((quad << 1) ^ cs) << 3)];
                        f16x8 v1 = *(const f16x8*)&vr[((((quad << 1) | 1) ^ cs) << 3)];
                        f16x4 vf0 = __builtin_shufflevector(v0, v0, 0, 1, 2, 3);
                        f16x4 vf1 = __builtin_shufflevector(v0, v0, 4, 5, 6, 7);
                        f16x4 vf2 = __builtin_shufflevector(v1, v1, 0, 1, 2, 3);
                        f16x4 vf3 = __builtin_shufflevector(v1, v1, 4, 5, 6, 7);
                        ofa[jo] = __builtin_amdgcn_mfma_f32_16x16x16f16(pa[0], vf0, ofa[jo], 0, 0, 0);
                        ofa[jo] = __builtin_amdgcn_mfma_f32_16x16x16f16(pa[1], vf1, ofa[jo], 0, 0, 0);
                        ofa[jo] = __builtin_amdgcn_mfma_f32_16x16x16f16(pa[2], vf2, ofa[jo], 0, 0, 0);
                        ofa[jo] = __builtin_amdgcn_mfma_f32_16x16x16f16(pa[3], vf3, ofa[jo], 0, 0, 0);
                        ofb[jo] = __builtin_amdgcn_mfma_f32_16x16x16f16(pb[0], vf0, ofb[jo], 0, 0, 0);
                        ofb[jo] = __builtin_amdgcn_mfma_f32_16x16x16f16(pb[1], vf1, ofb[jo], 0, 0, 0);
                        ofb[jo] = __builtin_amdgcn_mfma_f32_16x16x16f16(pb[2], vf2, ofb[jo], 0, 0, 0);
                        ofb[jo] = __builtin_amdgcn_mfma_f32_16x16x16f16(pb[3], vf3, ofb[jo], 0, 0, 0);
                    }
                    __builtin_amdgcn_s_setprio(0);
                }
            }

            __syncthreads();            // drains prefetch (overlapped) + guards buf reuse
            cur ^= 1;
        }

        // epilogue: complete row sums across quads (2 shfls), redistribute to C/D layout
        float la = lpa;
        la += __shfl_xor(la, 16, 64);
        la += __shfl_xor(la, 32, 64);
        float lb = lpb;
        lb += __shfl_xor(lb, 16, 64);
        lb += __shfl_xor(lb, 32, 64);
        float ia = 1.f / la, ib = 1.f / lb;
        #pragma unroll
        for (int r = 0; r < 4; ++r) {
            float iar = __shfl(ia, quad * 4 + r, 64);   // inv-sum for qrow quad*4+r
            float ibr = __shfl(ib, quad * 4 + r, 64);
            int row = s0 + w * 16 + quad * 4 + r;
            size_t obase = ((size_t)(b * SS + row)) * HH + (h0 << 6);
            #pragma unroll
            for (int jo = 0; jo < 4; ++jo) {
                attno[obase + jo * 16 + l15]      = f2h(ofa[jo][r] * iar);
                attno[obase + 64 + jo * 16 + l15] = f2h(ofb[jo][r] * ibr);
            }
        }
    }
#undef STAGE1
}

extern "C" void kernel_launch(void* const* d_in, const int* in_sizes, int n_in,
                              void* d_out, int out_size, void* d_ws, size_t ws_size,
                              hipStream_t stream) {
    const float* x      = (const float*)d_in[0];
    const float* w_norm = (const float*)d_in[1];
    const float* w_qkv  = (const float*)d_in[2];
    const float* w_out  = (const float*)d_in[3];
    float* out = (float*)d_out;
    char* ws = (char*)d_ws;

    float*  scal  = (float*)(ws + 0);           // [0]=sum|w_qkv|, [1]=sum|w_out|
    float*  rope  = (float*)(ws + 64);          // 2048*64 f32, ends 524352
    char*   xq    = (char*)(ws + 524352);       // 4096*2048 i8, ends 8912960
    float*  xsc   = (float*)(ws + 8912960);     // 4096 f32, ends 8929344
    char*   wq1   = (char*)(ws + 8929344);      // 3072*2048 i8, ends 15220800
    char*   wq2   = (char*)(ws + 15220800);     // 2048*2048 i8, ends 19415104
    ushort* qh    = (ushort*)(ws + 19415104);   // 4096*2048 f16, ends 36192320
    ushort* kh    = (ushort*)(ws + 36192320);   // 4096*512 f16, ends 40386624
    ushort* vT    = (ushort*)(ws + 40386624);   // 2*8*64*2048 f16, ends 44580928
    ushort* attno = (ushort*)(ws + 44580928);   // 4096*2048 f16, ends 61358144

    hipMemsetAsync(scal, 0, 64, stream);
    prep_kernel<<<2816, 256, 0, stream>>>(w_qkv, w_out, scal, rope);
    wquant_kernel<<<2560, 256, 0, stream>>>(w_qkv, w_out, (int*)wq1, (int*)wq2, scal);
    rmsq_kernel<<<MTOK, 256, 0, stream>>>(x, w_norm, (int*)xq, xsc);
    gemm_qkv_kernel<<<dim3(QKVO / 128, MTOK / 128), 256, 0, stream>>>(xq, wq1, xsc, scal + 0,
                                                                      1.0f / 6291456.0f, rope,
                                                                      qh, kh, vT);
    attn_mfma_kernel<<<dim3(SS / 64 / 2, NH_ / 2, 2), 256, 0, stream>>>(qh, kh, vT, attno);
    rowq_kernel<<<MTOK, 256, 0, stream>>>(attno, (int*)xq, xsc);
    gemm_i8_kernel<<<dim3(HH / 128, MTOK / 128), 256, 0, stream>>>(xq, wq2, out, xsc, scal + 1,
                                                                   1.0f / 4194304.0f, HH, HH);
}